// Round 12
// baseline (345.707 us; speedup 1.0000x reference)
//
#include <hip/hip_runtime.h>
#include <math.h>

#define NPTS 1024
#define S_   512
#define T_   8
#define K_   32
#define B_   2

typedef short bf16x8 __attribute__((ext_vector_type(8)));
typedef short short4v __attribute__((ext_vector_type(4)));
typedef float f32x4 __attribute__((ext_vector_type(4)));
typedef float vf2 __attribute__((ext_vector_type(2)));

static __device__ __forceinline__ short f2bf(float f) {
    unsigned u = __float_as_uint(f);
    unsigned r = (u + 0x7FFFu + ((u >> 16) & 1u)) >> 16;   // RNE
    return (short)r;
}

// ---- DPP wave-64 max reduction helper (result valid in lane 63) -----------
template <int CTRL>
static __device__ __forceinline__ float dppmaxf(float x) {
    int mv = __builtin_amdgcn_update_dpp(0, __float_as_int(x), CTRL, 0xF, 0xF, true);
    return fmaxf(x, __int_as_float(mv));
}
static __device__ __forceinline__ unsigned wavemax_bits_f(float x) {
    x = dppmaxf<0x111>(x); x = dppmaxf<0x112>(x);
    x = dppmaxf<0x114>(x); x = dppmaxf<0x118>(x);
    x = dppmaxf<0x142>(x); x = dppmaxf<0x143>(x);
    return (unsigned)__builtin_amdgcn_readlane(__float_as_int(x), 63);
}

static __device__ __forceinline__ vf2 pk_sub(vf2 a, vf2 b) { return a - b; }
static __device__ __forceinline__ vf2 pk_fma(vf2 a, vf2 b, vf2 c) {
#if __has_builtin(__builtin_elementwise_fma)
    return __builtin_elementwise_fma(a, b, c);
#else
    vf2 r; r[0] = __fmaf_rn(a[0], b[0], c[0]); r[1] = __fmaf_rn(a[1], b[1], c[1]); return r;
#endif
}
static __device__ __forceinline__ vf2 pk_min(vf2 a, vf2 b) {
#if __has_builtin(__builtin_elementwise_min)
    return __builtin_elementwise_min(a, b);
#else
    vf2 r; r[0] = fminf(a[0], b[0]); r[1] = fminf(a[1], b[1]); return r;
#endif
}
static __device__ __forceinline__ vf2 pk_max(vf2 a, vf2 b) {
#if __has_builtin(__builtin_elementwise_max)
    return __builtin_elementwise_max(a, b);
#else
    vf2 r; r[0] = fmaxf(a[0], b[0]); r[1] = fmaxf(a[1], b[1]); return r;
#endif
}

// static 8-way vf2 select (all indices compile-time -> cndmask tree, no scratch)
static __device__ __forceinline__ vf2 sel8(const vf2* a, int p) {
    vf2 lo01 = (p & 1) ? a[1] : a[0];
    vf2 lo23 = (p & 1) ? a[3] : a[2];
    vf2 hi01 = (p & 1) ? a[5] : a[4];
    vf2 hi23 = (p & 1) ? a[7] : a[6];
    vf2 lo = (p & 2) ? lo23 : lo01;
    vf2 hi = (p & 2) ? hi23 : hi01;
    return (p & 4) ? hi : lo;
}

// ---------------------------------------------------------------------------
// Kernel 1b: transpose points [bt][64][1024] f32 -> ptsT [bt][1024][64] bf16.
// ---------------------------------------------------------------------------
__global__ __launch_bounds__(256) void transpose_points(
    const float* __restrict__ pts, short* __restrict__ ptsT)
{
    int nt = blockIdx.x;      // 16 tiles of 64 points
    int bt = blockIdx.y;
    __shared__ float tile[64][65];
    int tid = threadIdx.x;
    for (int e = tid; e < 4096; e += 256) {
        int ci = e >> 6, nn = e & 63;
        tile[ci][nn] = pts[((size_t)bt * 64 + ci) * NPTS + nt * 64 + nn];
    }
    __syncthreads();
    for (int e = tid; e < 4096; e += 256) {
        int nn = e >> 6, ci = e & 63;
        ptsT[((size_t)bt * NPTS + nt * 64 + nn) * 64 + ci] = f2bf(tile[ci][nn]);
    }
}

// ---------------------------------------------------------------------------
// Kernel 1c: all three weight conversions in one launch (z = layer).
// wg0 [dt][64][100] (perm: points 0..64, gxyz 64..67), wg1 [dt][64][72],
// wg2 [dt][128][72].
// ---------------------------------------------------------------------------
__global__ __launch_bounds__(256) void prep_all(
    const float* __restrict__ w0, const float* __restrict__ w1,
    const float* __restrict__ w2,
    short* __restrict__ wg0, short* __restrict__ wg1, short* __restrict__ wg2)
{
    int z = blockIdx.y;
    int e = blockIdx.x * 256 + threadIdx.x;
    if (z == 0) {
        const int CI = 67, CIp = 100, CO = 64;
        if (e >= 4 * CO * CIp) return;
        int dt = e / (CO * CIp);
        int rem = e - dt * (CO * CIp);
        int co = rem / CIp;
        int ci = rem - co * CIp;
        float val = 0.0f;
        int cref = (ci < 64) ? (ci + 3) : ((ci < 67) ? (ci - 64) : -1);
        if (cref >= 0) val = w0[((size_t)co * CI + cref) * 4 + dt];
        wg0[e] = f2bf(val);
    } else if (z == 1) {
        const int CI = 64, CIp = 72, CO = 64;
        if (e >= 4 * CO * CIp) return;
        int dt = e / (CO * CIp);
        int rem = e - dt * (CO * CIp);
        int co = rem / CIp;
        int ci = rem - co * CIp;
        wg1[e] = f2bf((ci < CI) ? w1[((size_t)co * CI + ci) * 4 + dt] : 0.0f);
    } else {
        const int CI = 64, CIp = 72, CO = 128;
        if (e >= 4 * CO * CIp) return;
        int dt = e / (CO * CIp);
        int rem = e - dt * (CO * CIp);
        int co = rem / CIp;
        int ci = rem - co * CIp;
        wg2[e] = f2bf((ci < CI) ? w2[((size_t)co * CI + ci) * 4 + dt] : 0.0f);
    }
}

// ---------------------------------------------------------------------------
// MEGA KERNEL: blocks 0..1 = FPS producer (register-only chain, no LDS);
// blocks 2..513 = conv123 workers (verified r9/r11 math) polling fidx.
// Capacity-safe: LDS 52.3 KB -> 3 blocks/CU -> slots >= 514 blocks.
// ---------------------------------------------------------------------------
#define NWORK 512
#define SMEM_BYTES (256 * 100 * 2 + 8 * K_ * 4 + 8 * 3 * 4)

__global__ __launch_bounds__(256) void mega(
    const float* __restrict__ xyz, const short* __restrict__ ptsT,
    int* __restrict__ fidx,
    const short* __restrict__ wg0, const float* __restrict__ bb0,
    const float* __restrict__ gg0, const float* __restrict__ be0,
    const float* __restrict__ mm0, const float* __restrict__ vv0,
    const short* __restrict__ wg1, const float* __restrict__ bb1,
    const float* __restrict__ gg1, const float* __restrict__ be1,
    const float* __restrict__ mm1, const float* __restrict__ vv1,
    const short* __restrict__ wg2, const float* __restrict__ bb2,
    const float* __restrict__ gg2, const float* __restrict__ be2,
    const float* __restrict__ mm2, const float* __restrict__ vv2,
    float* __restrict__ out0, float* __restrict__ outPool)
{
    __shared__ __align__(16) char smem[SMEM_BYTES];
    int tid = threadIdx.x;

    if (blockIdx.x < 2) {
        // ========= FPS producer (single wave, register-only chain) =========
        if (tid >= 64) return;
        int b    = blockIdx.x;
        int lane = tid;
        const float* bx = xyz + (size_t)b * (T_ * 3 * NPTS);
        vf2 px2[8], py2[8], pz2[8], mind2[8];
#pragma unroll
        for (int q = 0; q < 4; ++q) {
            float4 vx = ((const float4*)(bx))[lane * 4 + q];
            float4 vy = ((const float4*)(bx + NPTS))[lane * 4 + q];
            float4 vz = ((const float4*)(bx + 2 * NPTS))[lane * 4 + q];
            px2[q*2]   = (vf2){vx.x, vx.y};  px2[q*2+1] = (vf2){vx.z, vx.w};
            py2[q*2]   = (vf2){vy.x, vy.y};  py2[q*2+1] = (vf2){vy.z, vy.w};
            pz2[q*2]   = (vf2){vz.x, vz.y};  pz2[q*2+1] = (vf2){vz.z, vz.w};
            mind2[q*2] = (vf2){1e10f, 1e10f}; mind2[q*2+1] = (vf2){1e10f, 1e10f};
        }
        int far = 0;
        float cx = bx[0], cy = bx[NPTS], cz = bx[2 * NPTS];

        for (int it = 0; it < S_; ++it) {
            if (lane == 0)
                __hip_atomic_store(&fidx[b * S_ + it], far + 1,
                                   __ATOMIC_RELAXED, __HIP_MEMORY_SCOPE_AGENT);
            vf2 c2x = (vf2){cx, cx}, c2y = (vf2){cy, cy}, c2z = (vf2){cz, cz};
#pragma unroll
            for (int q = 0; q < 8; ++q) {
                vf2 dx = pk_sub(px2[q], c2x);
                vf2 dy = pk_sub(py2[q], c2y);
                vf2 dz = pk_sub(pz2[q], c2z);
                vf2 d  = pk_fma(dz, dz, pk_fma(dy, dy, dx * dx));
                mind2[q] = pk_min(mind2[q], d);
            }
            vf2 t4a = pk_max(mind2[0], mind2[4]);
            vf2 t4b = pk_max(mind2[1], mind2[5]);
            vf2 t4c = pk_max(mind2[2], mind2[6]);
            vf2 t4d = pk_max(mind2[3], mind2[7]);
            vf2 t2a = pk_max(t4a, t4c);
            vf2 t2b = pk_max(t4b, t4d);
            vf2 t1  = pk_max(t2a, t2b);
            float lmax = fmaxf(t1[0], t1[1]);
            unsigned maxb = wavemax_bits_f(lmax);
            int cj[16];
#pragma unroll
            for (int j = 0; j < 16; ++j)
                cj[j] = (__float_as_uint(mind2[j >> 1][j & 1]) == maxb) ? j : 64;
            int m8[8], m4[4], m2v[2];
#pragma unroll
            for (int j = 0; j < 8; ++j) m8[j] = min(cj[j], cj[j + 8]);
#pragma unroll
            for (int j = 0; j < 4; ++j) m4[j] = min(m8[j], m8[j + 4]);
            m2v[0] = min(m4[0], m4[2]); m2v[1] = min(m4[1], m4[3]);
            int minj = min(m2v[0], m2v[1]);
            unsigned long long mk = __ballot(minj < 64);
            int l0 = __ffsll((long long)mk) - 1;     // lowest lane = smallest n
            int jw = __builtin_amdgcn_readlane(minj, l0);
            // candidate coords from registers (winner lane's select is valid)
            int p = (minj >> 1) & 7, e = minj & 1;
            vf2 hx = sel8(px2, p), hy = sel8(py2, p), hz = sel8(pz2, p);
            float sx = e ? hx[1] : hx[0];
            float sy = e ? hy[1] : hy[0];
            float sz = e ? hz[1] : hz[0];
            cx = __int_as_float(__builtin_amdgcn_readlane(__float_as_int(sx), l0));
            cy = __int_as_float(__builtin_amdgcn_readlane(__float_as_int(sy), l0));
            cz = __int_as_float(__builtin_amdgcn_readlane(__float_as_int(sz), l0));
            far = l0 * 16 + jw;
        }
        return;
    }

    // ================= conv123 worker =================
    const int CIp1 = 100, NK1 = 3;
    const int CIp2 = 72,  NK2 = 2;
    short* xsA    = (short*)smem;
    short* xsB    = xsA;                       // [256][72] overlay
    int*   gidx_l = (int*)(smem + 256 * 100 * 2);
    float* nxyz_l = (float*)(smem + 256 * 100 * 2 + 8 * K_ * 4);

    int w = blockIdx.x - 2;
    int lane = tid & 63;
    int wv   = tid >> 6;
    int l16  = lane & 15;
    int lq   = lane >> 4;

    for (int jobi = 0; jobi < 2; ++jobi) {
        int job = w + jobi * NWORK;
        int s = job >> 1, b = job & 1;
        __syncthreads();   // previous job's LDS reads retired

        // ---- poll for fidx[b,s] (value = far+1, 0 = not ready) ----
        int fid;
        {
            const int* p = &fidx[b * S_ + s];
            int v = 0, guard = 0;
            do {
                v = __hip_atomic_load(p, __ATOMIC_RELAXED, __HIP_MEMORY_SCOPE_AGENT);
                if (v) break;
                __builtin_amdgcn_s_sleep(2);
            } while (++guard < (1 << 24));
            fid = v - 1;
        }

        // ---- phase 1: ball query (verified, break-free) ----
        for (int half = 0; half < 2; ++half) {
            int tt = wv * 2 + half;
            int bt = b * T_ + tt;
            const float* bx = xyz + (size_t)bt * 3 * NPTS;
            float nx = bx[fid], ny = bx[NPTS + fid], nz = bx[2 * NPTS + fid];
            if (lane < 3) {
                float vvv = (lane == 0) ? nx : ((lane == 1) ? ny : nz);
                out0[(bt * 3 + lane) * S_ + s] = vvv;   // [B,t,3,S]
                nxyz_l[tt * 3 + lane] = vvv;
            }
            float A = __fmaf_rn(nz, nz, __fmaf_rn(ny, ny, __fmul_rn(nx, nx)));
            const float R2 = (float)(0.2 * 0.2);
            int count = 0, firstIdx = -1;
#pragma unroll
            for (int j = 0; j < 16; ++j) {
                int n = j * 64 + lane;
                float x = bx[n], y = bx[NPTS + n], z = bx[2 * NPTS + n];
                float Bn = __fmaf_rn(z, z, __fmaf_rn(y, y, __fmul_rn(x, x)));
                float C  = __fmaf_rn(nz, z, __fmaf_rn(ny, y, __fmul_rn(nx, x)));
                float sq = __fsub_rn(__fadd_rn(A, Bn), __fmul_rn(2.0f, C));
                bool valid = !(sq > R2);
                unsigned long long mb = __ballot(valid);
                if (valid) {
                    int pos = count + __popcll(mb & ((1ull << lane) - 1ull));
                    if (pos < K_) gidx_l[tt * K_ + pos] = n;
                }
                if (firstIdx < 0 && mb) firstIdx = j * 64 + (__ffsll((long long)mb) - 1);
                count += __popcll(mb);
            }
            if (count < K_) {
                for (int p = count + lane; p < K_; p += 64) gidx_l[tt * K_ + p] = firstIdx;
            }
        }
        __syncthreads();

        // ---- phase 2: gather into xsA[col][0..100) ----
        {
            int col = tid;
            int k = col & 31, tt = col >> 5;
            int bt = b * T_ + tt;
            short* xrow = &xsA[col * CIp1];
            int idx = gidx_l[tt * K_ + k];
            const short* prow = ptsT + ((size_t)bt * NPTS + idx) * 64;
#pragma unroll
            for (int c = 0; c < 8; ++c)
                ((int4*)xrow)[c] = ((const int4*)prow)[c];
#pragma unroll
            for (int ci = 0; ci < 3; ++ci)
                xrow[64 + ci] = f2bf(xyz[(size_t)(bt * 3 + ci) * NPTS + idx] - nxyz_l[tt * 3 + ci]);
            for (int ci = 67; ci < CIp1; ++ci) xrow[ci] = 0;
        }
        __syncthreads();

        // ---- phase 3: L1 GEMM ----
        {
            f32x4 acc[16];
#pragma unroll
            for (int nb = 0; nb < 16; ++nb) acc[nb] = (f32x4){0.f, 0.f, 0.f, 0.f};
#pragma unroll
            for (int ks = 0; ks < NK1; ++ks) {
                bf16x8 afr[4];
#pragma unroll
                for (int dt = 0; dt < 4; ++dt)
                    afr[dt] = *(const bf16x8*)&wg0[((size_t)(dt * 64 + wv * 16 + l16)) * CIp1 + ks * 32 + lq * 8];
                bf16x8 bfr[16];
#pragma unroll
                for (int cb = 0; cb < 16; ++cb)
                    bfr[cb] = *(const bf16x8*)&xsA[(cb * 16 + l16) * CIp1 + ks * 32 + lq * 8];
#pragma unroll
                for (int dt = 0; dt < 4; ++dt) {
#pragma unroll
                    for (int nb = 0; nb < 16; ++nb) {
                        int cb = nb + (dt - 1) * 2;
                        if (cb >= 0 && cb < 16)
                            acc[nb] = __builtin_amdgcn_mfma_f32_16x16x32_bf16(
                                afr[dt], bfr[cb], acc[nb], 0, 0, 0);
                    }
                }
            }
            __syncthreads();   // L1 LDS reads retired -> xsA reusable
            float sc0[4], c20[4];
#pragma unroll
            for (int j = 0; j < 4; ++j) {
                int co = wv * 16 + lq * 4 + j;
                float scv = gg0[co] / sqrtf(vv0[co] + 1e-5f);
                sc0[j] = scv;
                c20[j] = (bb0[co] - mm0[co]) * scv + be0[co];
            }
#pragma unroll
            for (int nb = 0; nb < 16; ++nb) {
                int col = nb * 16 + l16;
                short4v pk;
#pragma unroll
                for (int j = 0; j < 4; ++j)
                    pk[j] = f2bf(fmaxf(acc[nb][j] * sc0[j] + c20[j], 0.0f));
                *(short4v*)&xsB[col * CIp2 + wv * 16 + lq * 4] = pk;
            }
            *(int4*)&xsB[tid * CIp2 + 64] = make_int4(0, 0, 0, 0);
        }
        __syncthreads();

        // ---- phase 4: L2 GEMM ----
        {
            f32x4 acc[16];
#pragma unroll
            for (int nb = 0; nb < 16; ++nb) acc[nb] = (f32x4){0.f, 0.f, 0.f, 0.f};
#pragma unroll
            for (int ks = 0; ks < NK2; ++ks) {
                bf16x8 afr[4];
#pragma unroll
                for (int dt = 0; dt < 4; ++dt)
                    afr[dt] = *(const bf16x8*)&wg1[((size_t)(dt * 64 + wv * 16 + l16)) * CIp2 + ks * 32 + lq * 8];
                bf16x8 bfr[16];
#pragma unroll
                for (int cb = 0; cb < 16; ++cb)
                    bfr[cb] = *(const bf16x8*)&xsB[(cb * 16 + l16) * CIp2 + ks * 32 + lq * 8];
#pragma unroll
                for (int dt = 0; dt < 4; ++dt) {
#pragma unroll
                    for (int nb = 0; nb < 16; ++nb) {
                        int cb = nb + (dt - 1) * 2;
                        if (cb >= 0 && cb < 16)
                            acc[nb] = __builtin_amdgcn_mfma_f32_16x16x32_bf16(
                                afr[dt], bfr[cb], acc[nb], 0, 0, 0);
                    }
                }
            }
            __syncthreads();   // L2 LDS reads retired -> xsB writable
            float sc1[4], c21[4];
#pragma unroll
            for (int j = 0; j < 4; ++j) {
                int co = wv * 16 + lq * 4 + j;
                float scv = gg1[co] / sqrtf(vv1[co] + 1e-5f);
                sc1[j] = scv;
                c21[j] = (bb1[co] - mm1[co]) * scv + be1[co];
            }
#pragma unroll
            for (int nb = 0; nb < 16; ++nb) {
                int col = nb * 16 + l16;
                short4v pk;
#pragma unroll
                for (int j = 0; j < 4; ++j)
                    pk[j] = f2bf(fmaxf(acc[nb][j] * sc1[j] + c21[j], 0.0f));
                *(short4v*)&xsB[col * CIp2 + wv * 16 + lq * 4] = pk;
            }
        }
        __syncthreads();

        // ---- phase 5: L3 GEMM + pool ----
#pragma unroll
        for (int st = 0; st < 2; ++st) {
            f32x4 acc[16];
#pragma unroll
            for (int nb = 0; nb < 16; ++nb) acc[nb] = (f32x4){0.f, 0.f, 0.f, 0.f};
#pragma unroll
            for (int ks = 0; ks < NK2; ++ks) {
                bf16x8 afr[4];
#pragma unroll
                for (int dt = 0; dt < 4; ++dt)
                    afr[dt] = *(const bf16x8*)&wg2[((size_t)(dt * 128 + st * 64 + wv * 16 + l16)) * CIp2 + ks * 32 + lq * 8];
                bf16x8 bfr[16];
#pragma unroll
                for (int cb = 0; cb < 16; ++cb)
                    bfr[cb] = *(const bf16x8*)&xsB[(cb * 16 + l16) * CIp2 + ks * 32 + lq * 8];
#pragma unroll
                for (int dt = 0; dt < 4; ++dt) {
#pragma unroll
                    for (int nb = 0; nb < 16; ++nb) {
                        int cb = nb + (dt - 1) * 2;
                        if (cb >= 0 && cb < 16)
                            acc[nb] = __builtin_amdgcn_mfma_f32_16x16x32_bf16(
                                afr[dt], bfr[cb], acc[nb], 0, 0, 0);
                    }
                }
            }
            float sc2[4], c22[4];
#pragma unroll
            for (int j = 0; j < 4; ++j) {
                int co = st * 64 + wv * 16 + lq * 4 + j;
                float scv = gg2[co] / sqrtf(vv2[co] + 1e-5f);
                sc2[j] = scv;
                c22[j] = (bb2[co] - mm2[co]) * scv + be2[co];
            }
#pragma unroll
            for (int nbp = 0; nbp < 8; ++nbp) {       // t = nbp
#pragma unroll
                for (int j = 0; j < 4; ++j) {
                    float v0 = fmaxf(acc[2 * nbp][j] * sc2[j] + c22[j], 0.0f);
                    float v1 = fmaxf(acc[2 * nbp + 1][j] * sc2[j] + c22[j], 0.0f);
                    float v = fmaxf(v0, v1);
#pragma unroll
                    for (int off = 1; off < 16; off <<= 1)
                        v = fmaxf(v, __shfl_xor(v, off));
                    if (l16 == 0) {
                        int co = st * 64 + wv * 16 + lq * 4 + j;
                        outPool[((size_t)(b * T_ + nbp) * 128 + co) * S_ + s] = v;
                    }
                }
            }
        }
    }
}

// ---------------------------------------------------------------------------
extern "C" void kernel_launch(void* const* d_in, const int* in_sizes, int n_in,
                              void* d_out, int out_size, void* d_ws, size_t ws_size,
                              hipStream_t stream)
{
    (void)in_sizes; (void)n_in; (void)out_size; (void)ws_size;
    const float* xyz    = (const float*)d_in[0];
    const float* points = (const float*)d_in[1];
    const float* w0 = (const float*)d_in[2];
    const float* b0 = (const float*)d_in[3];
    const float* g0 = (const float*)d_in[4];
    const float* be0 = (const float*)d_in[5];
    const float* m0 = (const float*)d_in[6];
    const float* v0 = (const float*)d_in[7];
    const float* w1 = (const float*)d_in[8];
    const float* b1 = (const float*)d_in[9];
    const float* g1 = (const float*)d_in[10];
    const float* be1 = (const float*)d_in[11];
    const float* m1 = (const float*)d_in[12];
    const float* v1 = (const float*)d_in[13];
    const float* w2 = (const float*)d_in[14];
    const float* b2 = (const float*)d_in[15];
    const float* g2 = (const float*)d_in[16];
    const float* be2 = (const float*)d_in[17];
    const float* m2 = (const float*)d_in[18];
    const float* v2 = (const float*)d_in[19];

    float* out = (float*)d_out;
    char* ws = (char*)d_ws;
    // workspace map:
    //   fidx  @ 0        :   4 KB  (zeroed each launch; value = far+1)
    //   wg0   @ 3 MB     :  51.2 KB
    //   wg1   @ 3.25 MB  :  36.9 KB
    //   wg2   @ 3.5 MB   :  73.7 KB
    //   ptsT  @ 4  MB    :  2.1 MB
    int*   fidx = (int*)ws;
    short* wg0  = (short*)(ws + (size_t)(3 * 1024 * 1024));
    short* wg1  = (short*)(ws + (size_t)(3 * 1024 * 1024) + 256 * 1024);
    short* wg2  = (short*)(ws + (size_t)(3 * 1024 * 1024) + 512 * 1024);
    short* ptsT = (short*)(ws + (size_t)(4  * 1024 * 1024));

    hipMemsetAsync(fidx, 0, B_ * S_ * sizeof(int), stream);
    prep_all<<<dim3(144, 3), 256, 0, stream>>>(w0, w1, w2, wg0, wg1, wg2);
    transpose_points<<<dim3(16, B_ * T_), 256, 0, stream>>>(points, ptsT);

    mega<<<dim3(2 + NWORK), 256, 0, stream>>>(
        xyz, ptsT, fidx,
        wg0, b0, g0, be0, m0, v0,
        wg1, b1, g1, be1, m1, v1,
        wg2, b2, g2, be2, m2, v2,
        out, out + (size_t)B_ * T_ * 3 * S_);
}

// Round 13
// 331.320 us; speedup vs baseline: 1.0434x; 1.0434x over previous
//
#include <hip/hip_runtime.h>
#include <math.h>

#define NPTS 1024
#define S_   512
#define T_   8
#define K_   32
#define B_   2

typedef short bf16x8 __attribute__((ext_vector_type(8)));
typedef short short4v __attribute__((ext_vector_type(4)));
typedef float f32x4 __attribute__((ext_vector_type(4)));
typedef float vf2 __attribute__((ext_vector_type(2)));

static __device__ __forceinline__ short f2bf(float f) {
    unsigned u = __float_as_uint(f);
    unsigned r = (u + 0x7FFFu + ((u >> 16) & 1u)) >> 16;   // RNE
    return (short)r;
}

// ---- DPP wave-64 max reduction helper (result valid in lane 63) -----------
template <int CTRL>
static __device__ __forceinline__ float dppmaxf(float x) {
    int mv = __builtin_amdgcn_update_dpp(0, __float_as_int(x), CTRL, 0xF, 0xF, true);
    return fmaxf(x, __int_as_float(mv));
}
static __device__ __forceinline__ unsigned wavemax_bits_f(float x) {
    x = dppmaxf<0x111>(x); x = dppmaxf<0x112>(x);
    x = dppmaxf<0x114>(x); x = dppmaxf<0x118>(x);
    x = dppmaxf<0x142>(x); x = dppmaxf<0x143>(x);
    return (unsigned)__builtin_amdgcn_readlane(__float_as_int(x), 63);
}

static __device__ __forceinline__ vf2 pk_sub(vf2 a, vf2 b) { return a - b; }
static __device__ __forceinline__ vf2 pk_fma(vf2 a, vf2 b, vf2 c) {
#if __has_builtin(__builtin_elementwise_fma)
    return __builtin_elementwise_fma(a, b, c);
#else
    vf2 r; r[0] = __fmaf_rn(a[0], b[0], c[0]); r[1] = __fmaf_rn(a[1], b[1], c[1]); return r;
#endif
}
static __device__ __forceinline__ vf2 pk_min(vf2 a, vf2 b) {
#if __has_builtin(__builtin_elementwise_min)
    return __builtin_elementwise_min(a, b);
#else
    vf2 r; r[0] = fminf(a[0], b[0]); r[1] = fminf(a[1], b[1]); return r;
#endif
}
static __device__ __forceinline__ vf2 pk_max(vf2 a, vf2 b) {
#if __has_builtin(__builtin_elementwise_max)
    return __builtin_elementwise_max(a, b);
#else
    vf2 r; r[0] = fmaxf(a[0], b[0]); r[1] = fmaxf(a[1], b[1]); return r;
#endif
}

// ---------------------------------------------------------------------------
// Kernel 1b: transpose points [bt][64][1024] f32 -> ptsT [bt][1024][64] bf16.
// ---------------------------------------------------------------------------
__global__ __launch_bounds__(256) void transpose_points(
    const float* __restrict__ pts, short* __restrict__ ptsT)
{
    int nt = blockIdx.x;      // 16 tiles of 64 points
    int bt = blockIdx.y;
    __shared__ float tile[64][65];
    int tid = threadIdx.x;
    for (int e = tid; e < 4096; e += 256) {
        int ci = e >> 6, nn = e & 63;
        tile[ci][nn] = pts[((size_t)bt * 64 + ci) * NPTS + nt * 64 + nn];
    }
    __syncthreads();
    for (int e = tid; e < 4096; e += 256) {
        int nn = e >> 6, ci = e & 63;
        ptsT[((size_t)bt * NPTS + nt * 64 + nn) * 64 + ci] = f2bf(tile[ci][nn]);
    }
}

// ---------------------------------------------------------------------------
// Kernel 1c: all three weight conversions in one launch (z = layer).
// wg0 [dt][64][100] (perm: points 0..64, gxyz 64..67), wg1 [dt][64][72],
// wg2 [dt][128][72].
// ---------------------------------------------------------------------------
__global__ __launch_bounds__(256) void prep_all(
    const float* __restrict__ w0, const float* __restrict__ w1,
    const float* __restrict__ w2,
    short* __restrict__ wg0, short* __restrict__ wg1, short* __restrict__ wg2)
{
    int z = blockIdx.y;
    int e = blockIdx.x * 256 + threadIdx.x;
    if (z == 0) {
        const int CI = 67, CIp = 100, CO = 64;
        if (e >= 4 * CO * CIp) return;
        int dt = e / (CO * CIp);
        int rem = e - dt * (CO * CIp);
        int co = rem / CIp;
        int ci = rem - co * CIp;
        float val = 0.0f;
        int cref = (ci < 64) ? (ci + 3) : ((ci < 67) ? (ci - 64) : -1);
        if (cref >= 0) val = w0[((size_t)co * CI + cref) * 4 + dt];
        wg0[e] = f2bf(val);
    } else if (z == 1) {
        const int CI = 64, CIp = 72, CO = 64;
        if (e >= 4 * CO * CIp) return;
        int dt = e / (CO * CIp);
        int rem = e - dt * (CO * CIp);
        int co = rem / CIp;
        int ci = rem - co * CIp;
        wg1[e] = f2bf((ci < CI) ? w1[((size_t)co * CI + ci) * 4 + dt] : 0.0f);
    } else {
        const int CI = 64, CIp = 72, CO = 128;
        if (e >= 4 * CO * CIp) return;
        int dt = e / (CO * CIp);
        int rem = e - dt * (CO * CIp);
        int co = rem / CIp;
        int ci = rem - co * CIp;
        wg2[e] = f2bf((ci < CI) ? w2[((size_t)co * CI + ci) * 4 + dt] : 0.0f);
    }
}

// ---------------------------------------------------------------------------
// MEGA KERNEL: blocks 0..1 = FPS producer (r11-verified LDS-center chain,
// with the local-argmin-j tree overlapped against the DPP latency);
// blocks 2..257 = conv123 workers (verified r9/r11 math), 4 jobs each.
// Capacity-safe: LDS 52.3 KB -> 3 blocks/CU -> 768 slots >= 258 blocks.
// ---------------------------------------------------------------------------
#define NWORK 256
#define SMEM_BYTES (256 * 100 * 2 + 8 * K_ * 4 + 8 * 3 * 4)

__global__ __launch_bounds__(256) void mega(
    const float* __restrict__ xyz, const short* __restrict__ ptsT,
    int* __restrict__ fidx,
    const short* __restrict__ wg0, const float* __restrict__ bb0,
    const float* __restrict__ gg0, const float* __restrict__ be0,
    const float* __restrict__ mm0, const float* __restrict__ vv0,
    const short* __restrict__ wg1, const float* __restrict__ bb1,
    const float* __restrict__ gg1, const float* __restrict__ be1,
    const float* __restrict__ mm1, const float* __restrict__ vv1,
    const short* __restrict__ wg2, const float* __restrict__ bb2,
    const float* __restrict__ gg2, const float* __restrict__ be2,
    const float* __restrict__ mm2, const float* __restrict__ vv2,
    float* __restrict__ out0, float* __restrict__ outPool)
{
    __shared__ __align__(16) char smem[SMEM_BYTES];
    int tid = threadIdx.x;

    if (blockIdx.x < 2) {
        // ========= FPS producer (single wave, LDS center, r11-verified) =====
        if (tid >= 64) return;
        int b    = blockIdx.x;
        int lane = tid;
        float4* sc = (float4*)smem;
        const float* bx = xyz + (size_t)b * (T_ * 3 * NPTS);
        vf2 px2[8], py2[8], pz2[8], mind2[8];
#pragma unroll
        for (int q = 0; q < 4; ++q) {
            float4 vx = ((const float4*)(bx))[lane * 4 + q];
            float4 vy = ((const float4*)(bx + NPTS))[lane * 4 + q];
            float4 vz = ((const float4*)(bx + 2 * NPTS))[lane * 4 + q];
            px2[q*2]   = (vf2){vx.x, vx.y};  px2[q*2+1] = (vf2){vx.z, vx.w};
            py2[q*2]   = (vf2){vy.x, vy.y};  py2[q*2+1] = (vf2){vy.z, vy.w};
            pz2[q*2]   = (vf2){vz.x, vz.y};  pz2[q*2+1] = (vf2){vz.z, vz.w};
            int n0 = lane * 16 + q * 4;
            sc[n0+0] = make_float4(vx.x, vy.x, vz.x, 0.f);
            sc[n0+1] = make_float4(vx.y, vy.y, vz.y, 0.f);
            sc[n0+2] = make_float4(vx.z, vy.z, vz.z, 0.f);
            sc[n0+3] = make_float4(vx.w, vy.w, vz.w, 0.f);
            mind2[q*2] = (vf2){1e10f, 1e10f}; mind2[q*2+1] = (vf2){1e10f, 1e10f};
        }
        asm volatile("s_waitcnt lgkmcnt(0)" ::: "memory");  // wave-local LDS ordering

        int far = 0;
        for (int it = 0; it < S_; ++it) {
            if (lane == 0)
                __hip_atomic_store(&fidx[b * S_ + it], far + 1,
                                   __ATOMIC_RELAXED, __HIP_MEMORY_SCOPE_AGENT);
            float4 c = sc[far];
            vf2 c2x = (vf2){c.x, c.x}, c2y = (vf2){c.y, c.y}, c2z = (vf2){c.z, c.z};
#pragma unroll
            for (int q = 0; q < 8; ++q) {
                vf2 dx = pk_sub(px2[q], c2x);
                vf2 dy = pk_sub(py2[q], c2y);
                vf2 dz = pk_sub(pz2[q], c2z);
                vf2 d  = pk_fma(dz, dz, pk_fma(dy, dy, dx * dx));
                mind2[q] = pk_min(mind2[q], d);
            }
            vf2 t4a = pk_max(mind2[0], mind2[4]);
            vf2 t4b = pk_max(mind2[1], mind2[5]);
            vf2 t4c = pk_max(mind2[2], mind2[6]);
            vf2 t4d = pk_max(mind2[3], mind2[7]);
            vf2 t2a = pk_max(t4a, t4c);
            vf2 t2b = pk_max(t4b, t4d);
            vf2 t1  = pk_max(t2a, t2b);
            float lmax = fmaxf(t1[0], t1[1]);
            // issue the DPP chain, then overlap the LOCAL argmin-j tree with it
            unsigned maxb = wavemax_bits_f(lmax);
            unsigned lmb = __float_as_uint(lmax);
            int cj[16];
#pragma unroll
            for (int j = 0; j < 16; ++j)
                cj[j] = (__float_as_uint(mind2[j >> 1][j & 1]) == lmb) ? j : 64;
            int m8[8], m4[4], m2v[2];
#pragma unroll
            for (int j = 0; j < 8; ++j) m8[j] = min(cj[j], cj[j + 8]);
#pragma unroll
            for (int j = 0; j < 4; ++j) m4[j] = min(m8[j], m8[j + 4]);
            m2v[0] = min(m4[0], m4[2]); m2v[1] = min(m4[1], m4[3]);
            int minj_loc = min(m2v[0], m2v[1]);   // in [0,16): local match exists
            // winner = lowest lane whose local max equals the global max
            unsigned long long mk = __ballot(lmb == maxb);
            int l0 = __ffsll((long long)mk) - 1;
            int jw = __builtin_amdgcn_readlane(minj_loc, l0);
            far = l0 * 16 + jw;
        }
        return;
    }

    // ================= conv123 worker =================
    const int CIp1 = 100, NK1 = 3;
    const int CIp2 = 72,  NK2 = 2;
    short* xsA    = (short*)smem;
    short* xsB    = xsA;                       // [256][72] overlay
    int*   gidx_l = (int*)(smem + 256 * 100 * 2);
    float* nxyz_l = (float*)(smem + 256 * 100 * 2 + 8 * K_ * 4);

    int w = blockIdx.x - 2;
    int lane = tid & 63;
    int wv   = tid >> 6;
    int l16  = lane & 15;
    int lq   = lane >> 4;

    for (int jobi = 0; jobi < 4; ++jobi) {
        int job = w + jobi * NWORK;
        int s = job >> 1, b = job & 1;
        __syncthreads();   // previous job's LDS reads retired

        // ---- poll for fidx[b,s] (value = far+1, 0 = not ready) ----
        int fid;
        {
            const int* p = &fidx[b * S_ + s];
            int v = 0, guard = 0;
            do {
                v = __hip_atomic_load(p, __ATOMIC_RELAXED, __HIP_MEMORY_SCOPE_AGENT);
                if (v) break;
                __builtin_amdgcn_s_sleep(2);
            } while (++guard < (1 << 24));
            fid = v - 1;
        }

        // ---- phase 1: ball query (verified, break-free) ----
        for (int half = 0; half < 2; ++half) {
            int tt = wv * 2 + half;
            int bt = b * T_ + tt;
            const float* bx = xyz + (size_t)bt * 3 * NPTS;
            float nx = bx[fid], ny = bx[NPTS + fid], nz = bx[2 * NPTS + fid];
            if (lane < 3) {
                float vvv = (lane == 0) ? nx : ((lane == 1) ? ny : nz);
                out0[(bt * 3 + lane) * S_ + s] = vvv;   // [B,t,3,S]
                nxyz_l[tt * 3 + lane] = vvv;
            }
            float A = __fmaf_rn(nz, nz, __fmaf_rn(ny, ny, __fmul_rn(nx, nx)));
            const float R2 = (float)(0.2 * 0.2);
            int count = 0, firstIdx = -1;
#pragma unroll
            for (int j = 0; j < 16; ++j) {
                int n = j * 64 + lane;
                float x = bx[n], y = bx[NPTS + n], z = bx[2 * NPTS + n];
                float Bn = __fmaf_rn(z, z, __fmaf_rn(y, y, __fmul_rn(x, x)));
                float C  = __fmaf_rn(nz, z, __fmaf_rn(ny, y, __fmul_rn(nx, x)));
                float sq = __fsub_rn(__fadd_rn(A, Bn), __fmul_rn(2.0f, C));
                bool valid = !(sq > R2);
                unsigned long long mb = __ballot(valid);
                if (valid) {
                    int pos = count + __popcll(mb & ((1ull << lane) - 1ull));
                    if (pos < K_) gidx_l[tt * K_ + pos] = n;
                }
                if (firstIdx < 0 && mb) firstIdx = j * 64 + (__ffsll((long long)mb) - 1);
                count += __popcll(mb);
            }
            if (count < K_) {
                for (int p = count + lane; p < K_; p += 64) gidx_l[tt * K_ + p] = firstIdx;
            }
        }
        __syncthreads();

        // ---- phase 2: gather into xsA[col][0..100) ----
        {
            int col = tid;
            int k = col & 31, tt = col >> 5;
            int bt = b * T_ + tt;
            short* xrow = &xsA[col * CIp1];
            int idx = gidx_l[tt * K_ + k];
            const short* prow = ptsT + ((size_t)bt * NPTS + idx) * 64;
#pragma unroll
            for (int c = 0; c < 8; ++c)
                ((int4*)xrow)[c] = ((const int4*)prow)[c];
#pragma unroll
            for (int ci = 0; ci < 3; ++ci)
                xrow[64 + ci] = f2bf(xyz[(size_t)(bt * 3 + ci) * NPTS + idx] - nxyz_l[tt * 3 + ci]);
            for (int ci = 67; ci < CIp1; ++ci) xrow[ci] = 0;
        }
        __syncthreads();

        // ---- phase 3: L1 GEMM ----
        {
            f32x4 acc[16];
#pragma unroll
            for (int nb = 0; nb < 16; ++nb) acc[nb] = (f32x4){0.f, 0.f, 0.f, 0.f};
#pragma unroll
            for (int ks = 0; ks < NK1; ++ks) {
                bf16x8 afr[4];
#pragma unroll
                for (int dt = 0; dt < 4; ++dt)
                    afr[dt] = *(const bf16x8*)&wg0[((size_t)(dt * 64 + wv * 16 + l16)) * CIp1 + ks * 32 + lq * 8];
                bf16x8 bfr[16];
#pragma unroll
                for (int cb = 0; cb < 16; ++cb)
                    bfr[cb] = *(const bf16x8*)&xsA[(cb * 16 + l16) * CIp1 + ks * 32 + lq * 8];
#pragma unroll
                for (int dt = 0; dt < 4; ++dt) {
#pragma unroll
                    for (int nb = 0; nb < 16; ++nb) {
                        int cb = nb + (dt - 1) * 2;
                        if (cb >= 0 && cb < 16)
                            acc[nb] = __builtin_amdgcn_mfma_f32_16x16x32_bf16(
                                afr[dt], bfr[cb], acc[nb], 0, 0, 0);
                    }
                }
            }
            __syncthreads();   // L1 LDS reads retired -> xsA reusable
            float sc0[4], c20[4];
#pragma unroll
            for (int j = 0; j < 4; ++j) {
                int co = wv * 16 + lq * 4 + j;
                float scv = gg0[co] / sqrtf(vv0[co] + 1e-5f);
                sc0[j] = scv;
                c20[j] = (bb0[co] - mm0[co]) * scv + be0[co];
            }
#pragma unroll
            for (int nb = 0; nb < 16; ++nb) {
                int col = nb * 16 + l16;
                short4v pk;
#pragma unroll
                for (int j = 0; j < 4; ++j)
                    pk[j] = f2bf(fmaxf(acc[nb][j] * sc0[j] + c20[j], 0.0f));
                *(short4v*)&xsB[col * CIp2 + wv * 16 + lq * 4] = pk;
            }
            *(int4*)&xsB[tid * CIp2 + 64] = make_int4(0, 0, 0, 0);
        }
        __syncthreads();

        // ---- phase 4: L2 GEMM ----
        {
            f32x4 acc[16];
#pragma unroll
            for (int nb = 0; nb < 16; ++nb) acc[nb] = (f32x4){0.f, 0.f, 0.f, 0.f};
#pragma unroll
            for (int ks = 0; ks < NK2; ++ks) {
                bf16x8 afr[4];
#pragma unroll
                for (int dt = 0; dt < 4; ++dt)
                    afr[dt] = *(const bf16x8*)&wg1[((size_t)(dt * 64 + wv * 16 + l16)) * CIp2 + ks * 32 + lq * 8];
                bf16x8 bfr[16];
#pragma unroll
                for (int cb = 0; cb < 16; ++cb)
                    bfr[cb] = *(const bf16x8*)&xsB[(cb * 16 + l16) * CIp2 + ks * 32 + lq * 8];
#pragma unroll
                for (int dt = 0; dt < 4; ++dt) {
#pragma unroll
                    for (int nb = 0; nb < 16; ++nb) {
                        int cb = nb + (dt - 1) * 2;
                        if (cb >= 0 && cb < 16)
                            acc[nb] = __builtin_amdgcn_mfma_f32_16x16x32_bf16(
                                afr[dt], bfr[cb], acc[nb], 0, 0, 0);
                    }
                }
            }
            __syncthreads();   // L2 LDS reads retired -> xsB writable
            float sc1[4], c21[4];
#pragma unroll
            for (int j = 0; j < 4; ++j) {
                int co = wv * 16 + lq * 4 + j;
                float scv = gg1[co] / sqrtf(vv1[co] + 1e-5f);
                sc1[j] = scv;
                c21[j] = (bb1[co] - mm1[co]) * scv + be1[co];
            }
#pragma unroll
            for (int nb = 0; nb < 16; ++nb) {
                int col = nb * 16 + l16;
                short4v pk;
#pragma unroll
                for (int j = 0; j < 4; ++j)
                    pk[j] = f2bf(fmaxf(acc[nb][j] * sc1[j] + c21[j], 0.0f));
                *(short4v*)&xsB[col * CIp2 + wv * 16 + lq * 4] = pk;
            }
        }
        __syncthreads();

        // ---- phase 5: L3 GEMM + pool ----
#pragma unroll
        for (int st = 0; st < 2; ++st) {
            f32x4 acc[16];
#pragma unroll
            for (int nb = 0; nb < 16; ++nb) acc[nb] = (f32x4){0.f, 0.f, 0.f, 0.f};
#pragma unroll
            for (int ks = 0; ks < NK2; ++ks) {
                bf16x8 afr[4];
#pragma unroll
                for (int dt = 0; dt < 4; ++dt)
                    afr[dt] = *(const bf16x8*)&wg2[((size_t)(dt * 128 + st * 64 + wv * 16 + l16)) * CIp2 + ks * 32 + lq * 8];
                bf16x8 bfr[16];
#pragma unroll
                for (int cb = 0; cb < 16; ++cb)
                    bfr[cb] = *(const bf16x8*)&xsB[(cb * 16 + l16) * CIp2 + ks * 32 + lq * 8];
#pragma unroll
                for (int dt = 0; dt < 4; ++dt) {
#pragma unroll
                    for (int nb = 0; nb < 16; ++nb) {
                        int cb = nb + (dt - 1) * 2;
                        if (cb >= 0 && cb < 16)
                            acc[nb] = __builtin_amdgcn_mfma_f32_16x16x32_bf16(
                                afr[dt], bfr[cb], acc[nb], 0, 0, 0);
                    }
                }
            }
            float sc2[4], c22[4];
#pragma unroll
            for (int j = 0; j < 4; ++j) {
                int co = st * 64 + wv * 16 + lq * 4 + j;
                float scv = gg2[co] / sqrtf(vv2[co] + 1e-5f);
                sc2[j] = scv;
                c22[j] = (bb2[co] - mm2[co]) * scv + be2[co];
            }
#pragma unroll
            for (int nbp = 0; nbp < 8; ++nbp) {       // t = nbp
#pragma unroll
                for (int j = 0; j < 4; ++j) {
                    float v0 = fmaxf(acc[2 * nbp][j] * sc2[j] + c22[j], 0.0f);
                    float v1 = fmaxf(acc[2 * nbp + 1][j] * sc2[j] + c22[j], 0.0f);
                    float v = fmaxf(v0, v1);
#pragma unroll
                    for (int off = 1; off < 16; off <<= 1)
                        v = fmaxf(v, __shfl_xor(v, off));
                    if (l16 == 0) {
                        int co = st * 64 + wv * 16 + lq * 4 + j;
                        outPool[((size_t)(b * T_ + nbp) * 128 + co) * S_ + s] = v;
                    }
                }
            }
        }
    }
}

// ---------------------------------------------------------------------------
extern "C" void kernel_launch(void* const* d_in, const int* in_sizes, int n_in,
                              void* d_out, int out_size, void* d_ws, size_t ws_size,
                              hipStream_t stream)
{
    (void)in_sizes; (void)n_in; (void)out_size; (void)ws_size;
    const float* xyz    = (const float*)d_in[0];
    const float* points = (const float*)d_in[1];
    const float* w0 = (const float*)d_in[2];
    const float* b0 = (const float*)d_in[3];
    const float* g0 = (const float*)d_in[4];
    const float* be0 = (const float*)d_in[5];
    const float* m0 = (const float*)d_in[6];
    const float* v0 = (const float*)d_in[7];
    const float* w1 = (const float*)d_in[8];
    const float* b1 = (const float*)d_in[9];
    const float* g1 = (const float*)d_in[10];
    const float* be1 = (const float*)d_in[11];
    const float* m1 = (const float*)d_in[12];
    const float* v1 = (const float*)d_in[13];
    const float* w2 = (const float*)d_in[14];
    const float* b2 = (const float*)d_in[15];
    const float* g2 = (const float*)d_in[16];
    const float* be2 = (const float*)d_in[17];
    const float* m2 = (const float*)d_in[18];
    const float* v2 = (const float*)d_in[19];

    float* out = (float*)d_out;
    char* ws = (char*)d_ws;
    // workspace map:
    //   fidx  @ 0        :   4 KB  (zeroed each launch; value = far+1)
    //   wg0   @ 3 MB     :  51.2 KB
    //   wg1   @ 3.25 MB  :  36.9 KB
    //   wg2   @ 3.5 MB   :  73.7 KB
    //   ptsT  @ 4  MB    :  2.1 MB
    int*   fidx = (int*)ws;
    short* wg0  = (short*)(ws + (size_t)(3 * 1024 * 1024));
    short* wg1  = (short*)(ws + (size_t)(3 * 1024 * 1024) + 256 * 1024);
    short* wg2  = (short*)(ws + (size_t)(3 * 1024 * 1024) + 512 * 1024);
    short* ptsT = (short*)(ws + (size_t)(4  * 1024 * 1024));

    hipMemsetAsync(fidx, 0, B_ * S_ * sizeof(int), stream);
    prep_all<<<dim3(144, 3), 256, 0, stream>>>(w0, w1, w2, wg0, wg1, wg2);
    transpose_points<<<dim3(16, B_ * T_), 256, 0, stream>>>(points, ptsT);

    mega<<<dim3(2 + NWORK), 256, 0, stream>>>(
        xyz, ptsT, fidx,
        wg0, b0, g0, be0, m0, v0,
        wg1, b1, g1, be1, m1, v1,
        wg2, b2, g2, be2, m2, v2,
        out, out + (size_t)B_ * T_ * 3 * S_);
}

// Round 14
// 291.589 us; speedup vs baseline: 1.1856x; 1.1363x over previous
//
#include <hip/hip_runtime.h>
#include <math.h>

#define NPTS 1024
#define S_   512
#define T_   8
#define K_   32
#define B_   2

typedef short bf16x8 __attribute__((ext_vector_type(8)));
typedef short short4v __attribute__((ext_vector_type(4)));
typedef float f32x4 __attribute__((ext_vector_type(4)));
typedef float vf2 __attribute__((ext_vector_type(2)));

static __device__ __forceinline__ short f2bf(float f) {
    unsigned u = __float_as_uint(f);
    unsigned r = (u + 0x7FFFu + ((u >> 16) & 1u)) >> 16;   // RNE
    return (short)r;
}

// ---- DPP wave-64 max reduction helper (result valid in lane 63) -----------
template <int CTRL>
static __device__ __forceinline__ float dppmaxf(float x) {
    int mv = __builtin_amdgcn_update_dpp(0, __float_as_int(x), CTRL, 0xF, 0xF, true);
    return fmaxf(x, __int_as_float(mv));
}
static __device__ __forceinline__ unsigned wavemax_bits_f(float x) {
    x = dppmaxf<0x111>(x); x = dppmaxf<0x112>(x);
    x = dppmaxf<0x114>(x); x = dppmaxf<0x118>(x);
    x = dppmaxf<0x142>(x); x = dppmaxf<0x143>(x);
    return (unsigned)__builtin_amdgcn_readlane(__float_as_int(x), 63);
}

static __device__ __forceinline__ vf2 pk_sub(vf2 a, vf2 b) { return a - b; }
static __device__ __forceinline__ vf2 pk_fma(vf2 a, vf2 b, vf2 c) {
#if __has_builtin(__builtin_elementwise_fma)
    return __builtin_elementwise_fma(a, b, c);
#else
    vf2 r; r[0] = __fmaf_rn(a[0], b[0], c[0]); r[1] = __fmaf_rn(a[1], b[1], c[1]); return r;
#endif
}
static __device__ __forceinline__ vf2 pk_min(vf2 a, vf2 b) {
#if __has_builtin(__builtin_elementwise_min)
    return __builtin_elementwise_min(a, b);
#else
    vf2 r; r[0] = fminf(a[0], b[0]); r[1] = fminf(a[1], b[1]); return r;
#endif
}
static __device__ __forceinline__ vf2 pk_max(vf2 a, vf2 b) {
#if __has_builtin(__builtin_elementwise_max)
    return __builtin_elementwise_max(a, b);
#else
    vf2 r; r[0] = fmaxf(a[0], b[0]); r[1] = fmaxf(a[1], b[1]); return r;
#endif
}

// ---------------------------------------------------------------------------
// Kernel 1b: transpose points [bt][64][1024] f32 -> ptsT [bt][1024][64] bf16.
// ---------------------------------------------------------------------------
__global__ __launch_bounds__(256) void transpose_points(
    const float* __restrict__ pts, short* __restrict__ ptsT)
{
    int nt = blockIdx.x;      // 16 tiles of 64 points
    int bt = blockIdx.y;
    __shared__ float tile[64][65];
    int tid = threadIdx.x;
    for (int e = tid; e < 4096; e += 256) {
        int ci = e >> 6, nn = e & 63;
        tile[ci][nn] = pts[((size_t)bt * 64 + ci) * NPTS + nt * 64 + nn];
    }
    __syncthreads();
    for (int e = tid; e < 4096; e += 256) {
        int nn = e >> 6, ci = e & 63;
        ptsT[((size_t)bt * NPTS + nt * 64 + nn) * 64 + ci] = f2bf(tile[ci][nn]);
    }
}

// ---------------------------------------------------------------------------
// Kernel 1c: all three weight conversions in one launch (z = layer).
// wg0 [dt][64][100] (perm: points 0..64, gxyz 64..67), wg1 [dt][64][72],
// wg2 [dt][128][72].
// ---------------------------------------------------------------------------
__global__ __launch_bounds__(256) void prep_all(
    const float* __restrict__ w0, const float* __restrict__ w1,
    const float* __restrict__ w2,
    short* __restrict__ wg0, short* __restrict__ wg1, short* __restrict__ wg2)
{
    int z = blockIdx.y;
    int e = blockIdx.x * 256 + threadIdx.x;
    if (z == 0) {
        const int CI = 67, CIp = 100, CO = 64;
        if (e >= 4 * CO * CIp) return;
        int dt = e / (CO * CIp);
        int rem = e - dt * (CO * CIp);
        int co = rem / CIp;
        int ci = rem - co * CIp;
        float val = 0.0f;
        int cref = (ci < 64) ? (ci + 3) : ((ci < 67) ? (ci - 64) : -1);
        if (cref >= 0) val = w0[((size_t)co * CI + cref) * 4 + dt];
        wg0[e] = f2bf(val);
    } else if (z == 1) {
        const int CI = 64, CIp = 72, CO = 64;
        if (e >= 4 * CO * CIp) return;
        int dt = e / (CO * CIp);
        int rem = e - dt * (CO * CIp);
        int co = rem / CIp;
        int ci = rem - co * CIp;
        wg1[e] = f2bf((ci < CI) ? w1[((size_t)co * CI + ci) * 4 + dt] : 0.0f);
    } else {
        const int CI = 64, CIp = 72, CO = 128;
        if (e >= 4 * CO * CIp) return;
        int dt = e / (CO * CIp);
        int rem = e - dt * (CO * CIp);
        int co = rem / CIp;
        int ci = rem - co * CIp;
        wg2[e] = f2bf((ci < CI) ? w2[((size_t)co * CI + ci) * 4 + dt] : 0.0f);
    }
}

// ---------------------------------------------------------------------------
// MEGA KERNEL (r11 topology, verified): blocks 0..1 = FPS producer at wave
// priority 3; blocks 2..513 = conv123 workers (2 jobs each), tid0-only
// coarse->fine polling with LDS broadcast.
// Capacity-safe: LDS ~52.4 KB -> 3 blocks/CU -> 768 slots >= 514 blocks.
// ---------------------------------------------------------------------------
#define NWORK 512
#define SMEM_BYTES (256 * 100 * 2 + 8 * K_ * 4 + 8 * 3 * 4 + 8)

__global__ __launch_bounds__(256) void mega(
    const float* __restrict__ xyz, const short* __restrict__ ptsT,
    int* __restrict__ fidx,
    const short* __restrict__ wg0, const float* __restrict__ bb0,
    const float* __restrict__ gg0, const float* __restrict__ be0,
    const float* __restrict__ mm0, const float* __restrict__ vv0,
    const short* __restrict__ wg1, const float* __restrict__ bb1,
    const float* __restrict__ gg1, const float* __restrict__ be1,
    const float* __restrict__ mm1, const float* __restrict__ vv1,
    const short* __restrict__ wg2, const float* __restrict__ bb2,
    const float* __restrict__ gg2, const float* __restrict__ be2,
    const float* __restrict__ mm2, const float* __restrict__ vv2,
    float* __restrict__ out0, float* __restrict__ outPool)
{
    __shared__ __align__(16) char smem[SMEM_BYTES];
    int tid = threadIdx.x;

    if (blockIdx.x < 2) {
        // ========= FPS producer (single wave, LDS center, r11-verified) =====
        if (tid >= 64) return;
        __builtin_amdgcn_s_setprio(3);    // favor this latency-chain wave on its SIMD
        int b    = blockIdx.x;
        int lane = tid;
        float4* sc = (float4*)smem;
        const float* bx = xyz + (size_t)b * (T_ * 3 * NPTS);
        vf2 px2[8], py2[8], pz2[8], mind2[8];
#pragma unroll
        for (int q = 0; q < 4; ++q) {
            float4 vx = ((const float4*)(bx))[lane * 4 + q];
            float4 vy = ((const float4*)(bx + NPTS))[lane * 4 + q];
            float4 vz = ((const float4*)(bx + 2 * NPTS))[lane * 4 + q];
            px2[q*2]   = (vf2){vx.x, vx.y};  px2[q*2+1] = (vf2){vx.z, vx.w};
            py2[q*2]   = (vf2){vy.x, vy.y};  py2[q*2+1] = (vf2){vy.z, vy.w};
            pz2[q*2]   = (vf2){vz.x, vz.y};  pz2[q*2+1] = (vf2){vz.z, vz.w};
            int n0 = lane * 16 + q * 4;
            sc[n0+0] = make_float4(vx.x, vy.x, vz.x, 0.f);
            sc[n0+1] = make_float4(vx.y, vy.y, vz.y, 0.f);
            sc[n0+2] = make_float4(vx.z, vy.z, vz.z, 0.f);
            sc[n0+3] = make_float4(vx.w, vy.w, vz.w, 0.f);
            mind2[q*2] = (vf2){1e10f, 1e10f}; mind2[q*2+1] = (vf2){1e10f, 1e10f};
        }
        asm volatile("s_waitcnt lgkmcnt(0)" ::: "memory");  // wave-local LDS ordering

        int far = 0;
        for (int it = 0; it < S_; ++it) {
            if (lane == 0)
                __hip_atomic_store(&fidx[b * S_ + it], far + 1,
                                   __ATOMIC_RELAXED, __HIP_MEMORY_SCOPE_AGENT);
            float4 c = sc[far];
            vf2 c2x = (vf2){c.x, c.x}, c2y = (vf2){c.y, c.y}, c2z = (vf2){c.z, c.z};
#pragma unroll
            for (int q = 0; q < 8; ++q) {
                vf2 dx = pk_sub(px2[q], c2x);
                vf2 dy = pk_sub(py2[q], c2y);
                vf2 dz = pk_sub(pz2[q], c2z);
                vf2 d  = pk_fma(dz, dz, pk_fma(dy, dy, dx * dx));
                mind2[q] = pk_min(mind2[q], d);
            }
            vf2 t4a = pk_max(mind2[0], mind2[4]);
            vf2 t4b = pk_max(mind2[1], mind2[5]);
            vf2 t4c = pk_max(mind2[2], mind2[6]);
            vf2 t4d = pk_max(mind2[3], mind2[7]);
            vf2 t2a = pk_max(t4a, t4c);
            vf2 t2b = pk_max(t4b, t4d);
            vf2 t1  = pk_max(t2a, t2b);
            float lmax = fmaxf(t1[0], t1[1]);
            unsigned maxb = wavemax_bits_f(lmax);
            int cj[16];
#pragma unroll
            for (int j = 0; j < 16; ++j)
                cj[j] = (__float_as_uint(mind2[j >> 1][j & 1]) == maxb) ? j : 64;
            int m8[8], m4[4], m2v[2];
#pragma unroll
            for (int j = 0; j < 8; ++j) m8[j] = min(cj[j], cj[j + 8]);
#pragma unroll
            for (int j = 0; j < 4; ++j) m4[j] = min(m8[j], m8[j + 4]);
            m2v[0] = min(m4[0], m4[2]); m2v[1] = min(m4[1], m4[3]);
            int minj = min(m2v[0], m2v[1]);
            unsigned long long mk = __ballot(minj < 64);
            int l0 = __ffsll((long long)mk) - 1;     // lowest lane = smallest n
            int jw = __builtin_amdgcn_readlane(minj, l0);
            far = l0 * 16 + jw;
        }
        return;
    }

    // ================= conv123 worker =================
    const int CIp1 = 100, NK1 = 3;
    const int CIp2 = 72,  NK2 = 2;
    short* xsA    = (short*)smem;
    short* xsB    = xsA;                       // [256][72] overlay
    int*   gidx_l = (int*)(smem + 256 * 100 * 2);
    float* nxyz_l = (float*)(smem + 256 * 100 * 2 + 8 * K_ * 4);
    int*   fid_sh = (int*)(smem + 256 * 100 * 2 + 8 * K_ * 4 + 8 * 3 * 4);

    int w = blockIdx.x - 2;
    int lane = tid & 63;
    int wv   = tid >> 6;
    int l16  = lane & 15;
    int lq   = lane >> 4;

    for (int jobi = 0; jobi < 2; ++jobi) {
        int job = w + jobi * NWORK;
        int s = job >> 1, b = job & 1;
        __syncthreads();   // previous job's LDS reads retired

        // ---- tid0-only coarse->fine poll for fidx[b,s]; LDS broadcast ----
        if (tid == 0) {
            int guard = 0;
            int pre = s - 48;
            if (pre >= 0) {
                const int* pp = &fidx[b * S_ + pre];
                while (__hip_atomic_load(pp, __ATOMIC_RELAXED, __HIP_MEMORY_SCOPE_AGENT) == 0
                       && ++guard < (1 << 22))
                    __builtin_amdgcn_s_sleep(32);
            }
            const int* p = &fidx[b * S_ + s];
            int v = 0;
            do {
                v = __hip_atomic_load(p, __ATOMIC_RELAXED, __HIP_MEMORY_SCOPE_AGENT);
                if (v) break;
                __builtin_amdgcn_s_sleep(1);
            } while (++guard < (1 << 24));
            *fid_sh = v;
        }
        __syncthreads();
        int fid = *fid_sh - 1;

        // ---- phase 1: ball query (verified, break-free) ----
        for (int half = 0; half < 2; ++half) {
            int tt = wv * 2 + half;
            int bt = b * T_ + tt;
            const float* bx = xyz + (size_t)bt * 3 * NPTS;
            float nx = bx[fid], ny = bx[NPTS + fid], nz = bx[2 * NPTS + fid];
            if (lane < 3) {
                float vvv = (lane == 0) ? nx : ((lane == 1) ? ny : nz);
                out0[(bt * 3 + lane) * S_ + s] = vvv;   // [B,t,3,S]
                nxyz_l[tt * 3 + lane] = vvv;
            }
            float A = __fmaf_rn(nz, nz, __fmaf_rn(ny, ny, __fmul_rn(nx, nx)));
            const float R2 = (float)(0.2 * 0.2);
            int count = 0, firstIdx = -1;
#pragma unroll
            for (int j = 0; j < 16; ++j) {
                int n = j * 64 + lane;
                float x = bx[n], y = bx[NPTS + n], z = bx[2 * NPTS + n];
                float Bn = __fmaf_rn(z, z, __fmaf_rn(y, y, __fmul_rn(x, x)));
                float C  = __fmaf_rn(nz, z, __fmaf_rn(ny, y, __fmul_rn(nx, x)));
                float sq = __fsub_rn(__fadd_rn(A, Bn), __fmul_rn(2.0f, C));
                bool valid = !(sq > R2);
                unsigned long long mb = __ballot(valid);
                if (valid) {
                    int pos = count + __popcll(mb & ((1ull << lane) - 1ull));
                    if (pos < K_) gidx_l[tt * K_ + pos] = n;
                }
                if (firstIdx < 0 && mb) firstIdx = j * 64 + (__ffsll((long long)mb) - 1);
                count += __popcll(mb);
            }
            if (count < K_) {
                for (int p = count + lane; p < K_; p += 64) gidx_l[tt * K_ + p] = firstIdx;
            }
        }
        __syncthreads();

        // ---- phase 2: gather into xsA[col][0..100) ----
        {
            int col = tid;
            int k = col & 31, tt = col >> 5;
            int bt = b * T_ + tt;
            short* xrow = &xsA[col * CIp1];
            int idx = gidx_l[tt * K_ + k];
            const short* prow = ptsT + ((size_t)bt * NPTS + idx) * 64;
#pragma unroll
            for (int c = 0; c < 8; ++c)
                ((int4*)xrow)[c] = ((const int4*)prow)[c];
#pragma unroll
            for (int ci = 0; ci < 3; ++ci)
                xrow[64 + ci] = f2bf(xyz[(size_t)(bt * 3 + ci) * NPTS + idx] - nxyz_l[tt * 3 + ci]);
            for (int ci = 67; ci < CIp1; ++ci) xrow[ci] = 0;
        }
        __syncthreads();

        // ---- phase 3: L1 GEMM ----
        {
            f32x4 acc[16];
#pragma unroll
            for (int nb = 0; nb < 16; ++nb) acc[nb] = (f32x4){0.f, 0.f, 0.f, 0.f};
#pragma unroll
            for (int ks = 0; ks < NK1; ++ks) {
                bf16x8 afr[4];
#pragma unroll
                for (int dt = 0; dt < 4; ++dt)
                    afr[dt] = *(const bf16x8*)&wg0[((size_t)(dt * 64 + wv * 16 + l16)) * CIp1 + ks * 32 + lq * 8];
                bf16x8 bfr[16];
#pragma unroll
                for (int cb = 0; cb < 16; ++cb)
                    bfr[cb] = *(const bf16x8*)&xsA[(cb * 16 + l16) * CIp1 + ks * 32 + lq * 8];
#pragma unroll
                for (int dt = 0; dt < 4; ++dt) {
#pragma unroll
                    for (int nb = 0; nb < 16; ++nb) {
                        int cb = nb + (dt - 1) * 2;
                        if (cb >= 0 && cb < 16)
                            acc[nb] = __builtin_amdgcn_mfma_f32_16x16x32_bf16(
                                afr[dt], bfr[cb], acc[nb], 0, 0, 0);
                    }
                }
            }
            __syncthreads();   // L1 LDS reads retired -> xsA reusable
            float sc0[4], c20[4];
#pragma unroll
            for (int j = 0; j < 4; ++j) {
                int co = wv * 16 + lq * 4 + j;
                float scv = gg0[co] / sqrtf(vv0[co] + 1e-5f);
                sc0[j] = scv;
                c20[j] = (bb0[co] - mm0[co]) * scv + be0[co];
            }
#pragma unroll
            for (int nb = 0; nb < 16; ++nb) {
                int col = nb * 16 + l16;
                short4v pk;
#pragma unroll
                for (int j = 0; j < 4; ++j)
                    pk[j] = f2bf(fmaxf(acc[nb][j] * sc0[j] + c20[j], 0.0f));
                *(short4v*)&xsB[col * CIp2 + wv * 16 + lq * 4] = pk;
            }
            *(int4*)&xsB[tid * CIp2 + 64] = make_int4(0, 0, 0, 0);
        }
        __syncthreads();

        // ---- phase 4: L2 GEMM ----
        {
            f32x4 acc[16];
#pragma unroll
            for (int nb = 0; nb < 16; ++nb) acc[nb] = (f32x4){0.f, 0.f, 0.f, 0.f};
#pragma unroll
            for (int ks = 0; ks < NK2; ++ks) {
                bf16x8 afr[4];
#pragma unroll
                for (int dt = 0; dt < 4; ++dt)
                    afr[dt] = *(const bf16x8*)&wg1[((size_t)(dt * 64 + wv * 16 + l16)) * CIp2 + ks * 32 + lq * 8];
                bf16x8 bfr[16];
#pragma unroll
                for (int cb = 0; cb < 16; ++cb)
                    bfr[cb] = *(const bf16x8*)&xsB[(cb * 16 + l16) * CIp2 + ks * 32 + lq * 8];
#pragma unroll
                for (int dt = 0; dt < 4; ++dt) {
#pragma unroll
                    for (int nb = 0; nb < 16; ++nb) {
                        int cb = nb + (dt - 1) * 2;
                        if (cb >= 0 && cb < 16)
                            acc[nb] = __builtin_amdgcn_mfma_f32_16x16x32_bf16(
                                afr[dt], bfr[cb], acc[nb], 0, 0, 0);
                    }
                }
            }
            __syncthreads();   // L2 LDS reads retired -> xsB writable
            float sc1[4], c21[4];
#pragma unroll
            for (int j = 0; j < 4; ++j) {
                int co = wv * 16 + lq * 4 + j;
                float scv = gg1[co] / sqrtf(vv1[co] + 1e-5f);
                sc1[j] = scv;
                c21[j] = (bb1[co] - mm1[co]) * scv + be1[co];
            }
#pragma unroll
            for (int nb = 0; nb < 16; ++nb) {
                int col = nb * 16 + l16;
                short4v pk;
#pragma unroll
                for (int j = 0; j < 4; ++j)
                    pk[j] = f2bf(fmaxf(acc[nb][j] * sc1[j] + c21[j], 0.0f));
                *(short4v*)&xsB[col * CIp2 + wv * 16 + lq * 4] = pk;
            }
        }
        __syncthreads();

        // ---- phase 5: L3 GEMM + pool ----
#pragma unroll
        for (int st = 0; st < 2; ++st) {
            f32x4 acc[16];
#pragma unroll
            for (int nb = 0; nb < 16; ++nb) acc[nb] = (f32x4){0.f, 0.f, 0.f, 0.f};
#pragma unroll
            for (int ks = 0; ks < NK2; ++ks) {
                bf16x8 afr[4];
#pragma unroll
                for (int dt = 0; dt < 4; ++dt)
                    afr[dt] = *(const bf16x8*)&wg2[((size_t)(dt * 128 + st * 64 + wv * 16 + l16)) * CIp2 + ks * 32 + lq * 8];
                bf16x8 bfr[16];
#pragma unroll
                for (int cb = 0; cb < 16; ++cb)
                    bfr[cb] = *(const bf16x8*)&xsB[(cb * 16 + l16) * CIp2 + ks * 32 + lq * 8];
#pragma unroll
                for (int dt = 0; dt < 4; ++dt) {
#pragma unroll
                    for (int nb = 0; nb < 16; ++nb) {
                        int cb = nb + (dt - 1) * 2;
                        if (cb >= 0 && cb < 16)
                            acc[nb] = __builtin_amdgcn_mfma_f32_16x16x32_bf16(
                                afr[dt], bfr[cb], acc[nb], 0, 0, 0);
                    }
                }
            }
            float sc2[4], c22[4];
#pragma unroll
            for (int j = 0; j < 4; ++j) {
                int co = st * 64 + wv * 16 + lq * 4 + j;
                float scv = gg2[co] / sqrtf(vv2[co] + 1e-5f);
                sc2[j] = scv;
                c22[j] = (bb2[co] - mm2[co]) * scv + be2[co];
            }
#pragma unroll
            for (int nbp = 0; nbp < 8; ++nbp) {       // t = nbp
#pragma unroll
                for (int j = 0; j < 4; ++j) {
                    float v0 = fmaxf(acc[2 * nbp][j] * sc2[j] + c22[j], 0.0f);
                    float v1 = fmaxf(acc[2 * nbp + 1][j] * sc2[j] + c22[j], 0.0f);
                    float v = fmaxf(v0, v1);
#pragma unroll
                    for (int off = 1; off < 16; off <<= 1)
                        v = fmaxf(v, __shfl_xor(v, off));
                    if (l16 == 0) {
                        int co = st * 64 + wv * 16 + lq * 4 + j;
                        outPool[((size_t)(b * T_ + nbp) * 128 + co) * S_ + s] = v;
                    }
                }
            }
        }
    }
}

// ---------------------------------------------------------------------------
extern "C" void kernel_launch(void* const* d_in, const int* in_sizes, int n_in,
                              void* d_out, int out_size, void* d_ws, size_t ws_size,
                              hipStream_t stream)
{
    (void)in_sizes; (void)n_in; (void)out_size; (void)ws_size;
    const float* xyz    = (const float*)d_in[0];
    const float* points = (const float*)d_in[1];
    const float* w0 = (const float*)d_in[2];
    const float* b0 = (const float*)d_in[3];
    const float* g0 = (const float*)d_in[4];
    const float* be0 = (const float*)d_in[5];
    const float* m0 = (const float*)d_in[6];
    const float* v0 = (const float*)d_in[7];
    const float* w1 = (const float*)d_in[8];
    const float* b1 = (const float*)d_in[9];
    const float* g1 = (const float*)d_in[10];
    const float* be1 = (const float*)d_in[11];
    const float* m1 = (const float*)d_in[12];
    const float* v1 = (const float*)d_in[13];
    const float* w2 = (const float*)d_in[14];
    const float* b2 = (const float*)d_in[15];
    const float* g2 = (const float*)d_in[16];
    const float* be2 = (const float*)d_in[17];
    const float* m2 = (const float*)d_in[18];
    const float* v2 = (const float*)d_in[19];

    float* out = (float*)d_out;
    char* ws = (char*)d_ws;
    // workspace map:
    //   fidx  @ 0        :   4 KB  (zeroed each launch; value = far+1)
    //   wg0   @ 3 MB     :  51.2 KB
    //   wg1   @ 3.25 MB  :  36.9 KB
    //   wg2   @ 3.5 MB   :  73.7 KB
    //   ptsT  @ 4  MB    :  2.1 MB
    int*   fidx = (int*)ws;
    short* wg0  = (short*)(ws + (size_t)(3 * 1024 * 1024));
    short* wg1  = (short*)(ws + (size_t)(3 * 1024 * 1024) + 256 * 1024);
    short* wg2  = (short*)(ws + (size_t)(3 * 1024 * 1024) + 512 * 1024);
    short* ptsT = (short*)(ws + (size_t)(4  * 1024 * 1024));

    hipMemsetAsync(fidx, 0, B_ * S_ * sizeof(int), stream);
    prep_all<<<dim3(144, 3), 256, 0, stream>>>(w0, w1, w2, wg0, wg1, wg2);
    transpose_points<<<dim3(16, B_ * T_), 256, 0, stream>>>(points, ptsT);

    mega<<<dim3(2 + NWORK), 256, 0, stream>>>(
        xyz, ptsT, fidx,
        wg0, b0, g0, be0, m0, v0,
        wg1, b1, g1, be1, m1, v1,
        wg2, b2, g2, be2, m2, v2,
        out, out + (size_t)B_ * T_ * 3 * S_);
}

// Round 15
// 288.703 us; speedup vs baseline: 1.1974x; 1.0100x over previous
//
#include <hip/hip_runtime.h>
#include <math.h>

#define NPTS 1024
#define S_   512
#define T_   8
#define K_   32
#define B_   2

typedef short bf16x8 __attribute__((ext_vector_type(8)));
typedef short short4v __attribute__((ext_vector_type(4)));
typedef float f32x4 __attribute__((ext_vector_type(4)));
typedef float vf2 __attribute__((ext_vector_type(2)));

static __device__ __forceinline__ short f2bf(float f) {
    unsigned u = __float_as_uint(f);
    unsigned r = (u + 0x7FFFu + ((u >> 16) & 1u)) >> 16;   // RNE
    return (short)r;
}

// ---- DPP wave-64 max reduction helper (result valid in lane 63) -----------
template <int CTRL>
static __device__ __forceinline__ float dppmaxf(float x) {
    int mv = __builtin_amdgcn_update_dpp(0, __float_as_int(x), CTRL, 0xF, 0xF, true);
    return fmaxf(x, __int_as_float(mv));
}
static __device__ __forceinline__ unsigned wavemax_bits_f(float x) {
    x = dppmaxf<0x111>(x); x = dppmaxf<0x112>(x);
    x = dppmaxf<0x114>(x); x = dppmaxf<0x118>(x);
    x = dppmaxf<0x142>(x); x = dppmaxf<0x143>(x);
    return (unsigned)__builtin_amdgcn_readlane(__float_as_int(x), 63);
}

static __device__ __forceinline__ vf2 pk_sub(vf2 a, vf2 b) { return a - b; }
static __device__ __forceinline__ vf2 pk_fma(vf2 a, vf2 b, vf2 c) {
#if __has_builtin(__builtin_elementwise_fma)
    return __builtin_elementwise_fma(a, b, c);
#else
    vf2 r; r[0] = __fmaf_rn(a[0], b[0], c[0]); r[1] = __fmaf_rn(a[1], b[1], c[1]); return r;
#endif
}
static __device__ __forceinline__ vf2 pk_min(vf2 a, vf2 b) {
#if __has_builtin(__builtin_elementwise_min)
    return __builtin_elementwise_min(a, b);
#else
    vf2 r; r[0] = fminf(a[0], b[0]); r[1] = fminf(a[1], b[1]); return r;
#endif
}

// 3-input exact max/min (clang fuses to v_max3_f32 / v_min3_i32 on gfx9+)
static __device__ __forceinline__ float max3f(float a, float b, float c) {
    return fmaxf(fmaxf(a, b), c);
}
static __device__ __forceinline__ int min3i(int a, int b, int c) {
    return min(min(a, b), c);
}

// ---------------------------------------------------------------------------
// Kernel 1b: transpose points [bt][64][1024] f32 -> ptsT [bt][1024][64] bf16.
// ---------------------------------------------------------------------------
__global__ __launch_bounds__(256) void transpose_points(
    const float* __restrict__ pts, short* __restrict__ ptsT)
{
    int nt = blockIdx.x;      // 16 tiles of 64 points
    int bt = blockIdx.y;
    __shared__ float tile[64][65];
    int tid = threadIdx.x;
    for (int e = tid; e < 4096; e += 256) {
        int ci = e >> 6, nn = e & 63;
        tile[ci][nn] = pts[((size_t)bt * 64 + ci) * NPTS + nt * 64 + nn];
    }
    __syncthreads();
    for (int e = tid; e < 4096; e += 256) {
        int nn = e >> 6, ci = e & 63;
        ptsT[((size_t)bt * NPTS + nt * 64 + nn) * 64 + ci] = f2bf(tile[ci][nn]);
    }
}

// ---------------------------------------------------------------------------
// Kernel 1c: all three weight conversions in one launch (z = layer).
// wg0 [dt][64][100] (perm: points 0..64, gxyz 64..67), wg1 [dt][64][72],
// wg2 [dt][128][72].
// ---------------------------------------------------------------------------
__global__ __launch_bounds__(256) void prep_all(
    const float* __restrict__ w0, const float* __restrict__ w1,
    const float* __restrict__ w2,
    short* __restrict__ wg0, short* __restrict__ wg1, short* __restrict__ wg2)
{
    int z = blockIdx.y;
    int e = blockIdx.x * 256 + threadIdx.x;
    if (z == 0) {
        const int CI = 67, CIp = 100, CO = 64;
        if (e >= 4 * CO * CIp) return;
        int dt = e / (CO * CIp);
        int rem = e - dt * (CO * CIp);
        int co = rem / CIp;
        int ci = rem - co * CIp;
        float val = 0.0f;
        int cref = (ci < 64) ? (ci + 3) : ((ci < 67) ? (ci - 64) : -1);
        if (cref >= 0) val = w0[((size_t)co * CI + cref) * 4 + dt];
        wg0[e] = f2bf(val);
    } else if (z == 1) {
        const int CI = 64, CIp = 72, CO = 64;
        if (e >= 4 * CO * CIp) return;
        int dt = e / (CO * CIp);
        int rem = e - dt * (CO * CIp);
        int co = rem / CIp;
        int ci = rem - co * CIp;
        wg1[e] = f2bf((ci < CI) ? w1[((size_t)co * CI + ci) * 4 + dt] : 0.0f);
    } else {
        const int CI = 64, CIp = 72, CO = 128;
        if (e >= 4 * CO * CIp) return;
        int dt = e / (CO * CIp);
        int rem = e - dt * (CO * CIp);
        int co = rem / CIp;
        int ci = rem - co * CIp;
        wg2[e] = f2bf((ci < CI) ? w2[((size_t)co * CI + ci) * 4 + dt] : 0.0f);
    }
}

// ---------------------------------------------------------------------------
// MEGA KERNEL (r14 topology, verified 291.6us): blocks 0..1 = FPS producer
// at wave priority 3 (3-ary reduction trees this round); blocks 2..513 =
// conv123 workers (2 jobs each), tid0-only coarse->fine polling.
// Capacity-safe: LDS ~52.4 KB -> 3 blocks/CU -> 768 slots >= 514 blocks.
// ---------------------------------------------------------------------------
#define NWORK 512
#define SMEM_BYTES (256 * 100 * 2 + 8 * K_ * 4 + 8 * 3 * 4 + 8)

__global__ __launch_bounds__(256) void mega(
    const float* __restrict__ xyz, const short* __restrict__ ptsT,
    int* __restrict__ fidx,
    const short* __restrict__ wg0, const float* __restrict__ bb0,
    const float* __restrict__ gg0, const float* __restrict__ be0,
    const float* __restrict__ mm0, const float* __restrict__ vv0,
    const short* __restrict__ wg1, const float* __restrict__ bb1,
    const float* __restrict__ gg1, const float* __restrict__ be1,
    const float* __restrict__ mm1, const float* __restrict__ vv1,
    const short* __restrict__ wg2, const float* __restrict__ bb2,
    const float* __restrict__ gg2, const float* __restrict__ be2,
    const float* __restrict__ mm2, const float* __restrict__ vv2,
    float* __restrict__ out0, float* __restrict__ outPool)
{
    __shared__ __align__(16) char smem[SMEM_BYTES];
    int tid = threadIdx.x;

    if (blockIdx.x < 2) {
        // ========= FPS producer (single wave, LDS center, r11-verified) =====
        if (tid >= 64) return;
        __builtin_amdgcn_s_setprio(3);    // favor this latency-chain wave on its SIMD
        int b    = blockIdx.x;
        int lane = tid;
        float4* sc = (float4*)smem;
        const float* bx = xyz + (size_t)b * (T_ * 3 * NPTS);
        vf2 px2[8], py2[8], pz2[8], mind2[8];
#pragma unroll
        for (int q = 0; q < 4; ++q) {
            float4 vx = ((const float4*)(bx))[lane * 4 + q];
            float4 vy = ((const float4*)(bx + NPTS))[lane * 4 + q];
            float4 vz = ((const float4*)(bx + 2 * NPTS))[lane * 4 + q];
            px2[q*2]   = (vf2){vx.x, vx.y};  px2[q*2+1] = (vf2){vx.z, vx.w};
            py2[q*2]   = (vf2){vy.x, vy.y};  py2[q*2+1] = (vf2){vy.z, vy.w};
            pz2[q*2]   = (vf2){vz.x, vz.y};  pz2[q*2+1] = (vf2){vz.z, vz.w};
            int n0 = lane * 16 + q * 4;
            sc[n0+0] = make_float4(vx.x, vy.x, vz.x, 0.f);
            sc[n0+1] = make_float4(vx.y, vy.y, vz.y, 0.f);
            sc[n0+2] = make_float4(vx.z, vy.z, vz.z, 0.f);
            sc[n0+3] = make_float4(vx.w, vy.w, vz.w, 0.f);
            mind2[q*2] = (vf2){1e10f, 1e10f}; mind2[q*2+1] = (vf2){1e10f, 1e10f};
        }
        asm volatile("s_waitcnt lgkmcnt(0)" ::: "memory");  // wave-local LDS ordering

        int far = 0;
        for (int it = 0; it < S_; ++it) {
            if (lane == 0)
                __hip_atomic_store(&fidx[b * S_ + it], far + 1,
                                   __ATOMIC_RELAXED, __HIP_MEMORY_SCOPE_AGENT);
            float4 c = sc[far];
            vf2 c2x = (vf2){c.x, c.x}, c2y = (vf2){c.y, c.y}, c2z = (vf2){c.z, c.z};
#pragma unroll
            for (int q = 0; q < 8; ++q) {
                vf2 dx = pk_sub(px2[q], c2x);
                vf2 dy = pk_sub(py2[q], c2y);
                vf2 dz = pk_sub(pz2[q], c2z);
                vf2 d  = pk_fma(dz, dz, pk_fma(dy, dy, dx * dx));
                mind2[q] = pk_min(mind2[q], d);
            }
            // per-lane max over 16 via 3-ary tree (exact; fuses to v_max3_f32)
            #define M_(j) (mind2[(j) >> 1][(j) & 1])
            float g0 = max3f(M_(0),  M_(1),  M_(2));
            float g1 = max3f(M_(3),  M_(4),  M_(5));
            float g2 = max3f(M_(6),  M_(7),  M_(8));
            float g3 = max3f(M_(9),  M_(10), M_(11));
            float g4 = max3f(M_(12), M_(13), M_(14));
            float h0 = max3f(g0, g1, g2);
            float h1 = max3f(g3, g4, M_(15));
            float lmax = fmaxf(h0, h1);
            unsigned maxb = wavemax_bits_f(lmax);
            int cj[16];
#pragma unroll
            for (int j = 0; j < 16; ++j)
                cj[j] = (__float_as_uint(M_(j)) == maxb) ? j : 64;
            #undef M_
            // smallest matching j via 3-ary min tree (fuses to v_min3_i32)
            int n0m = min3i(cj[0],  cj[1],  cj[2]);
            int n1m = min3i(cj[3],  cj[4],  cj[5]);
            int n2m = min3i(cj[6],  cj[7],  cj[8]);
            int n3m = min3i(cj[9],  cj[10], cj[11]);
            int n4m = min3i(cj[12], cj[13], cj[14]);
            int p0m = min3i(n0m, n1m, n2m);
            int p1m = min3i(n3m, n4m, cj[15]);
            int minj = min(p0m, p1m);
            unsigned long long mk = __ballot(minj < 64);
            int l0 = __ffsll((long long)mk) - 1;     // lowest lane = smallest n
            int jw = __builtin_amdgcn_readlane(minj, l0);
            far = l0 * 16 + jw;
        }
        return;
    }

    // ================= conv123 worker =================
    const int CIp1 = 100, NK1 = 3;
    const int CIp2 = 72,  NK2 = 2;
    short* xsA    = (short*)smem;
    short* xsB    = xsA;                       // [256][72] overlay
    int*   gidx_l = (int*)(smem + 256 * 100 * 2);
    float* nxyz_l = (float*)(smem + 256 * 100 * 2 + 8 * K_ * 4);
    int*   fid_sh = (int*)(smem + 256 * 100 * 2 + 8 * K_ * 4 + 8 * 3 * 4);

    int w = blockIdx.x - 2;
    int lane = tid & 63;
    int wv   = tid >> 6;
    int l16  = lane & 15;
    int lq   = lane >> 4;

    for (int jobi = 0; jobi < 2; ++jobi) {
        int job = w + jobi * NWORK;
        int s = job >> 1, b = job & 1;
        __syncthreads();   // previous job's LDS reads retired

        // ---- tid0-only coarse->fine poll for fidx[b,s]; LDS broadcast ----
        if (tid == 0) {
            int guard = 0;
            int pre = s - 48;
            if (pre >= 0) {
                const int* pp = &fidx[b * S_ + pre];
                while (__hip_atomic_load(pp, __ATOMIC_RELAXED, __HIP_MEMORY_SCOPE_AGENT) == 0
                       && ++guard < (1 << 22))
                    __builtin_amdgcn_s_sleep(32);
            }
            const int* p = &fidx[b * S_ + s];
            int v = 0;
            do {
                v = __hip_atomic_load(p, __ATOMIC_RELAXED, __HIP_MEMORY_SCOPE_AGENT);
                if (v) break;
                __builtin_amdgcn_s_sleep(1);
            } while (++guard < (1 << 24));
            *fid_sh = v;
        }
        __syncthreads();
        int fid = *fid_sh - 1;

        // ---- phase 1: ball query (verified, break-free) ----
        for (int half = 0; half < 2; ++half) {
            int tt = wv * 2 + half;
            int bt = b * T_ + tt;
            const float* bx = xyz + (size_t)bt * 3 * NPTS;
            float nx = bx[fid], ny = bx[NPTS + fid], nz = bx[2 * NPTS + fid];
            if (lane < 3) {
                float vvv = (lane == 0) ? nx : ((lane == 1) ? ny : nz);
                out0[(bt * 3 + lane) * S_ + s] = vvv;   // [B,t,3,S]
                nxyz_l[tt * 3 + lane] = vvv;
            }
            float A = __fmaf_rn(nz, nz, __fmaf_rn(ny, ny, __fmul_rn(nx, nx)));
            const float R2 = (float)(0.2 * 0.2);
            int count = 0, firstIdx = -1;
#pragma unroll
            for (int j = 0; j < 16; ++j) {
                int n = j * 64 + lane;
                float x = bx[n], y = bx[NPTS + n], z = bx[2 * NPTS + n];
                float Bn = __fmaf_rn(z, z, __fmaf_rn(y, y, __fmul_rn(x, x)));
                float C  = __fmaf_rn(nz, z, __fmaf_rn(ny, y, __fmul_rn(nx, x)));
                float sq = __fsub_rn(__fadd_rn(A, Bn), __fmul_rn(2.0f, C));
                bool valid = !(sq > R2);
                unsigned long long mb = __ballot(valid);
                if (valid) {
                    int pos = count + __popcll(mb & ((1ull << lane) - 1ull));
                    if (pos < K_) gidx_l[tt * K_ + pos] = n;
                }
                if (firstIdx < 0 && mb) firstIdx = j * 64 + (__ffsll((long long)mb) - 1);
                count += __popcll(mb);
            }
            if (count < K_) {
                for (int p = count + lane; p < K_; p += 64) gidx_l[tt * K_ + p] = firstIdx;
            }
        }
        __syncthreads();

        // ---- phase 2: gather into xsA[col][0..100) ----
        {
            int col = tid;
            int k = col & 31, tt = col >> 5;
            int bt = b * T_ + tt;
            short* xrow = &xsA[col * CIp1];
            int idx = gidx_l[tt * K_ + k];
            const short* prow = ptsT + ((size_t)bt * NPTS + idx) * 64;
#pragma unroll
            for (int c = 0; c < 8; ++c)
                ((int4*)xrow)[c] = ((const int4*)prow)[c];
#pragma unroll
            for (int ci = 0; ci < 3; ++ci)
                xrow[64 + ci] = f2bf(xyz[(size_t)(bt * 3 + ci) * NPTS + idx] - nxyz_l[tt * 3 + ci]);
            for (int ci = 67; ci < CIp1; ++ci) xrow[ci] = 0;
        }
        __syncthreads();

        // ---- phase 3: L1 GEMM ----
        {
            f32x4 acc[16];
#pragma unroll
            for (int nb = 0; nb < 16; ++nb) acc[nb] = (f32x4){0.f, 0.f, 0.f, 0.f};
#pragma unroll
            for (int ks = 0; ks < NK1; ++ks) {
                bf16x8 afr[4];
#pragma unroll
                for (int dt = 0; dt < 4; ++dt)
                    afr[dt] = *(const bf16x8*)&wg0[((size_t)(dt * 64 + wv * 16 + l16)) * CIp1 + ks * 32 + lq * 8];
                bf16x8 bfr[16];
#pragma unroll
                for (int cb = 0; cb < 16; ++cb)
                    bfr[cb] = *(const bf16x8*)&xsA[(cb * 16 + l16) * CIp1 + ks * 32 + lq * 8];
#pragma unroll
                for (int dt = 0; dt < 4; ++dt) {
#pragma unroll
                    for (int nb = 0; nb < 16; ++nb) {
                        int cb = nb + (dt - 1) * 2;
                        if (cb >= 0 && cb < 16)
                            acc[nb] = __builtin_amdgcn_mfma_f32_16x16x32_bf16(
                                afr[dt], bfr[cb], acc[nb], 0, 0, 0);
                    }
                }
            }
            __syncthreads();   // L1 LDS reads retired -> xsA reusable
            float sc0[4], c20[4];
#pragma unroll
            for (int j = 0; j < 4; ++j) {
                int co = wv * 16 + lq * 4 + j;
                float scv = gg0[co] / sqrtf(vv0[co] + 1e-5f);
                sc0[j] = scv;
                c20[j] = (bb0[co] - mm0[co]) * scv + be0[co];
            }
#pragma unroll
            for (int nb = 0; nb < 16; ++nb) {
                int col = nb * 16 + l16;
                short4v pk;
#pragma unroll
                for (int j = 0; j < 4; ++j)
                    pk[j] = f2bf(fmaxf(acc[nb][j] * sc0[j] + c20[j], 0.0f));
                *(short4v*)&xsB[col * CIp2 + wv * 16 + lq * 4] = pk;
            }
            *(int4*)&xsB[tid * CIp2 + 64] = make_int4(0, 0, 0, 0);
        }
        __syncthreads();

        // ---- phase 4: L2 GEMM ----
        {
            f32x4 acc[16];
#pragma unroll
            for (int nb = 0; nb < 16; ++nb) acc[nb] = (f32x4){0.f, 0.f, 0.f, 0.f};
#pragma unroll
            for (int ks = 0; ks < NK2; ++ks) {
                bf16x8 afr[4];
#pragma unroll
                for (int dt = 0; dt < 4; ++dt)
                    afr[dt] = *(const bf16x8*)&wg1[((size_t)(dt * 64 + wv * 16 + l16)) * CIp2 + ks * 32 + lq * 8];
                bf16x8 bfr[16];
#pragma unroll
                for (int cb = 0; cb < 16; ++cb)
                    bfr[cb] = *(const bf16x8*)&xsB[(cb * 16 + l16) * CIp2 + ks * 32 + lq * 8];
#pragma unroll
                for (int dt = 0; dt < 4; ++dt) {
#pragma unroll
                    for (int nb = 0; nb < 16; ++nb) {
                        int cb = nb + (dt - 1) * 2;
                        if (cb >= 0 && cb < 16)
                            acc[nb] = __builtin_amdgcn_mfma_f32_16x16x32_bf16(
                                afr[dt], bfr[cb], acc[nb], 0, 0, 0);
                    }
                }
            }
            __syncthreads();   // L2 LDS reads retired -> xsB writable
            float sc1[4], c21[4];
#pragma unroll
            for (int j = 0; j < 4; ++j) {
                int co = wv * 16 + lq * 4 + j;
                float scv = gg1[co] / sqrtf(vv1[co] + 1e-5f);
                sc1[j] = scv;
                c21[j] = (bb1[co] - mm1[co]) * scv + be1[co];
            }
#pragma unroll
            for (int nb = 0; nb < 16; ++nb) {
                int col = nb * 16 + l16;
                short4v pk;
#pragma unroll
                for (int j = 0; j < 4; ++j)
                    pk[j] = f2bf(fmaxf(acc[nb][j] * sc1[j] + c21[j], 0.0f));
                *(short4v*)&xsB[col * CIp2 + wv * 16 + lq * 4] = pk;
            }
        }
        __syncthreads();

        // ---- phase 5: L3 GEMM + pool ----
#pragma unroll
        for (int st = 0; st < 2; ++st) {
            f32x4 acc[16];
#pragma unroll
            for (int nb = 0; nb < 16; ++nb) acc[nb] = (f32x4){0.f, 0.f, 0.f, 0.f};
#pragma unroll
            for (int ks = 0; ks < NK2; ++ks) {
                bf16x8 afr[4];
#pragma unroll
                for (int dt = 0; dt < 4; ++dt)
                    afr[dt] = *(const bf16x8*)&wg2[((size_t)(dt * 128 + st * 64 + wv * 16 + l16)) * CIp2 + ks * 32 + lq * 8];
                bf16x8 bfr[16];
#pragma unroll
                for (int cb = 0; cb < 16; ++cb)
                    bfr[cb] = *(const bf16x8*)&xsB[(cb * 16 + l16) * CIp2 + ks * 32 + lq * 8];
#pragma unroll
                for (int dt = 0; dt < 4; ++dt) {
#pragma unroll
                    for (int nb = 0; nb < 16; ++nb) {
                        int cb = nb + (dt - 1) * 2;
                        if (cb >= 0 && cb < 16)
                            acc[nb] = __builtin_amdgcn_mfma_f32_16x16x32_bf16(
                                afr[dt], bfr[cb], acc[nb], 0, 0, 0);
                    }
                }
            }
            float sc2[4], c22[4];
#pragma unroll
            for (int j = 0; j < 4; ++j) {
                int co = st * 64 + wv * 16 + lq * 4 + j;
                float scv = gg2[co] / sqrtf(vv2[co] + 1e-5f);
                sc2[j] = scv;
                c22[j] = (bb2[co] - mm2[co]) * scv + be2[co];
            }
#pragma unroll
            for (int nbp = 0; nbp < 8; ++nbp) {       // t = nbp
#pragma unroll
                for (int j = 0; j < 4; ++j) {
                    float v0 = fmaxf(acc[2 * nbp][j] * sc2[j] + c22[j], 0.0f);
                    float v1 = fmaxf(acc[2 * nbp + 1][j] * sc2[j] + c22[j], 0.0f);
                    float v = fmaxf(v0, v1);
#pragma unroll
                    for (int off = 1; off < 16; off <<= 1)
                        v = fmaxf(v, __shfl_xor(v, off));
                    if (l16 == 0) {
                        int co = st * 64 + wv * 16 + lq * 4 + j;
                        outPool[((size_t)(b * T_ + nbp) * 128 + co) * S_ + s] = v;
                    }
                }
            }
        }
    }
}

// ---------------------------------------------------------------------------
extern "C" void kernel_launch(void* const* d_in, const int* in_sizes, int n_in,
                              void* d_out, int out_size, void* d_ws, size_t ws_size,
                              hipStream_t stream)
{
    (void)in_sizes; (void)n_in; (void)out_size; (void)ws_size;
    const float* xyz    = (const float*)d_in[0];
    const float* points = (const float*)d_in[1];
    const float* w0 = (const float*)d_in[2];
    const float* b0 = (const float*)d_in[3];
    const float* g0 = (const float*)d_in[4];
    const float* be0 = (const float*)d_in[5];
    const float* m0 = (const float*)d_in[6];
    const float* v0 = (const float*)d_in[7];
    const float* w1 = (const float*)d_in[8];
    const float* b1 = (const float*)d_in[9];
    const float* g1 = (const float*)d_in[10];
    const float* be1 = (const float*)d_in[11];
    const float* m1 = (const float*)d_in[12];
    const float* v1 = (const float*)d_in[13];
    const float* w2 = (const float*)d_in[14];
    const float* b2 = (const float*)d_in[15];
    const float* g2 = (const float*)d_in[16];
    const float* be2 = (const float*)d_in[17];
    const float* m2 = (const float*)d_in[18];
    const float* v2 = (const float*)d_in[19];

    float* out = (float*)d_out;
    char* ws = (char*)d_ws;
    // workspace map:
    //   fidx  @ 0        :   4 KB  (zeroed each launch; value = far+1)
    //   wg0   @ 3 MB     :  51.2 KB
    //   wg1   @ 3.25 MB  :  36.9 KB
    //   wg2   @ 3.5 MB   :  73.7 KB
    //   ptsT  @ 4  MB    :  2.1 MB
    int*   fidx = (int*)ws;
    short* wg0  = (short*)(ws + (size_t)(3 * 1024 * 1024));
    short* wg1  = (short*)(ws + (size_t)(3 * 1024 * 1024) + 256 * 1024);
    short* wg2  = (short*)(ws + (size_t)(3 * 1024 * 1024) + 512 * 1024);
    short* ptsT = (short*)(ws + (size_t)(4  * 1024 * 1024));

    hipMemsetAsync(fidx, 0, B_ * S_ * sizeof(int), stream);
    prep_all<<<dim3(144, 3), 256, 0, stream>>>(w0, w1, w2, wg0, wg1, wg2);
    transpose_points<<<dim3(16, B_ * T_), 256, 0, stream>>>(points, ptsT);

    mega<<<dim3(2 + NWORK), 256, 0, stream>>>(
        xyz, ptsT, fidx,
        wg0, b0, g0, be0, m0, v0,
        wg1, b1, g1, be1, m1, v1,
        wg2, b2, g2, be2, m2, v2,
        out, out + (size_t)B_ * T_ * 3 * S_);
}

// Round 17
// 285.715 us; speedup vs baseline: 1.2100x; 1.0105x over previous
//
#include <hip/hip_runtime.h>
#include <math.h>

#define NPTS 1024
#define S_   512
#define T_   8
#define K_   32
#define B_   2

typedef short bf16x8 __attribute__((ext_vector_type(8)));
typedef short short4v __attribute__((ext_vector_type(4)));
typedef float f32x4 __attribute__((ext_vector_type(4)));
typedef float vf2 __attribute__((ext_vector_type(2)));

static __device__ __forceinline__ short f2bf(float f) {
    unsigned u = __float_as_uint(f);
    unsigned r = (u + 0x7FFFu + ((u >> 16) & 1u)) >> 16;   // RNE
    return (short)r;
}

// ---- DPP wave-64 max reduction helper (result valid in lane 63) -----------
template <int CTRL>
static __device__ __forceinline__ float dppmaxf(float x) {
    int mv = __builtin_amdgcn_update_dpp(0, __float_as_int(x), CTRL, 0xF, 0xF, true);
    return fmaxf(x, __int_as_float(mv));
}
static __device__ __forceinline__ unsigned wavemax_bits_f(float x) {
    x = dppmaxf<0x111>(x); x = dppmaxf<0x112>(x);
    x = dppmaxf<0x114>(x); x = dppmaxf<0x118>(x);
    x = dppmaxf<0x142>(x); x = dppmaxf<0x143>(x);
    return (unsigned)__builtin_amdgcn_readlane(__float_as_int(x), 63);
}

static __device__ __forceinline__ vf2 pk_sub(vf2 a, vf2 b) { return a - b; }
static __device__ __forceinline__ vf2 pk_fma(vf2 a, vf2 b, vf2 c) {
#if __has_builtin(__builtin_elementwise_fma)
    return __builtin_elementwise_fma(a, b, c);
#else
    vf2 r; r[0] = __fmaf_rn(a[0], b[0], c[0]); r[1] = __fmaf_rn(a[1], b[1], c[1]); return r;
#endif
}
static __device__ __forceinline__ vf2 pk_min(vf2 a, vf2 b) {
#if __has_builtin(__builtin_elementwise_min)
    return __builtin_elementwise_min(a, b);
#else
    vf2 r; r[0] = fminf(a[0], b[0]); r[1] = fminf(a[1], b[1]); return r;
#endif
}

// 3-input exact max/min (clang fuses to v_max3_f32 / v_min3_i32 on gfx9+)
static __device__ __forceinline__ float max3f(float a, float b, float c) {
    return fmaxf(fmaxf(a, b), c);
}
static __device__ __forceinline__ int min3i(int a, int b, int c) {
    return min(min(a, b), c);
}

// ---------------------------------------------------------------------------
// Kernel 1b: transpose points [bt][64][1024] f32 -> ptsT [bt][1024][64] bf16.
// (separate kernel: stream-order publication, Guideline-16-safe)
// ---------------------------------------------------------------------------
__global__ __launch_bounds__(256) void transpose_points(
    const float* __restrict__ pts, short* __restrict__ ptsT)
{
    int nt = blockIdx.x;      // 16 tiles of 64 points
    int bt = blockIdx.y;
    __shared__ float tile[64][65];
    int tid = threadIdx.x;
    for (int e = tid; e < 4096; e += 256) {
        int ci = e >> 6, nn = e & 63;
        tile[ci][nn] = pts[((size_t)bt * 64 + ci) * NPTS + nt * 64 + nn];
    }
    __syncthreads();
    for (int e = tid; e < 4096; e += 256) {
        int nn = e >> 6, ci = e & 63;
        ptsT[((size_t)bt * NPTS + nt * 64 + nn) * 64 + ci] = f2bf(tile[ci][nn]);
    }
}

// ---------------------------------------------------------------------------
// Kernel 1c: all three weight conversions in one launch (z = layer).
// wg0 [dt][64][100] (perm: points 0..64, gxyz 64..67), wg1 [dt][64][72],
// wg2 [dt][128][72].
// ---------------------------------------------------------------------------
__global__ __launch_bounds__(256) void prep_all(
    const float* __restrict__ w0, const float* __restrict__ w1,
    const float* __restrict__ w2,
    short* __restrict__ wg0, short* __restrict__ wg1, short* __restrict__ wg2)
{
    int z = blockIdx.y;
    int e = blockIdx.x * 256 + threadIdx.x;
    if (z == 0) {
        const int CI = 67, CIp = 100, CO = 64;
        if (e >= 4 * CO * CIp) return;
        int dt = e / (CO * CIp);
        int rem = e - dt * (CO * CIp);
        int co = rem / CIp;
        int ci = rem - co * CIp;
        float val = 0.0f;
        int cref = (ci < 64) ? (ci + 3) : ((ci < 67) ? (ci - 64) : -1);
        if (cref >= 0) val = w0[((size_t)co * CI + cref) * 4 + dt];
        wg0[e] = f2bf(val);
    } else if (z == 1) {
        const int CI = 64, CIp = 72, CO = 64;
        if (e >= 4 * CO * CIp) return;
        int dt = e / (CO * CIp);
        int rem = e - dt * (CO * CIp);
        int co = rem / CIp;
        int ci = rem - co * CIp;
        wg1[e] = f2bf((ci < CI) ? w1[((size_t)co * CI + ci) * 4 + dt] : 0.0f);
    } else {
        const int CI = 64, CIp = 72, CO = 128;
        if (e >= 4 * CO * CIp) return;
        int dt = e / (CO * CIp);
        int rem = e - dt * (CO * CIp);
        int co = rem / CIp;
        int ci = rem - co * CIp;
        wg2[e] = f2bf((ci < CI) ? w2[((size_t)co * CI + ci) * 4 + dt] : 0.0f);
    }
}

// ---------------------------------------------------------------------------
// MEGA KERNEL (r15 topology, verified 288.7us): blocks 0..1 = FPS producer
// at prio 3 with 3-ary trees + DPP-shadowed LOCAL min-tree; blocks 2..513 =
// conv123 workers (2 jobs each), tid0-only coarse->fine polling.
// Capacity-safe: LDS ~52.4 KB -> 3 blocks/CU -> 768 slots >= 514 blocks.
// ---------------------------------------------------------------------------
#define NWORK 512
#define SMEM_BYTES (256 * 100 * 2 + 8 * K_ * 4 + 8 * 3 * 4 + 8)

__global__ __launch_bounds__(256) void mega(
    const float* __restrict__ xyz, const short* __restrict__ ptsT,
    int* __restrict__ fidx,
    const short* __restrict__ wg0, const float* __restrict__ bb0,
    const float* __restrict__ gg0, const float* __restrict__ be0,
    const float* __restrict__ mm0, const float* __restrict__ vv0,
    const short* __restrict__ wg1, const float* __restrict__ bb1,
    const float* __restrict__ gg1, const float* __restrict__ be1,
    const float* __restrict__ mm1, const float* __restrict__ vv1,
    const short* __restrict__ wg2, const float* __restrict__ bb2,
    const float* __restrict__ gg2, const float* __restrict__ be2,
    const float* __restrict__ mm2, const float* __restrict__ vv2,
    float* __restrict__ out0, float* __restrict__ outPool)
{
    __shared__ __align__(16) char smem[SMEM_BYTES];
    int tid = threadIdx.x;

    if (blockIdx.x < 2) {
        // ========= FPS producer (single wave, LDS center, verified) =========
        if (tid >= 64) return;
        __builtin_amdgcn_s_setprio(3);    // favor this latency-chain wave
        int b    = blockIdx.x;
        int lane = tid;
        float4* sc = (float4*)smem;
        const float* bx = xyz + (size_t)b * (T_ * 3 * NPTS);
        vf2 px2[8], py2[8], pz2[8], mind2[8];
#pragma unroll
        for (int q = 0; q < 4; ++q) {
            float4 vx = ((const float4*)(bx))[lane * 4 + q];
            float4 vy = ((const float4*)(bx + NPTS))[lane * 4 + q];
            float4 vz = ((const float4*)(bx + 2 * NPTS))[lane * 4 + q];
            px2[q*2]   = (vf2){vx.x, vx.y};  px2[q*2+1] = (vf2){vx.z, vx.w};
            py2[q*2]   = (vf2){vy.x, vy.y};  py2[q*2+1] = (vf2){vy.z, vy.w};
            pz2[q*2]   = (vf2){vz.x, vz.y};  pz2[q*2+1] = (vf2){vz.z, vz.w};
            int n0 = lane * 16 + q * 4;
            sc[n0+0] = make_float4(vx.x, vy.x, vz.x, 0.f);
            sc[n0+1] = make_float4(vx.y, vy.y, vz.y, 0.f);
            sc[n0+2] = make_float4(vx.z, vy.z, vz.z, 0.f);
            sc[n0+3] = make_float4(vx.w, vy.w, vz.w, 0.f);
            mind2[q*2] = (vf2){1e10f, 1e10f}; mind2[q*2+1] = (vf2){1e10f, 1e10f};
        }
        asm volatile("s_waitcnt lgkmcnt(0)" ::: "memory");  // wave-local LDS ordering

        int far = 0;
        for (int it = 0; it < S_; ++it) {
            if (lane == 0)
                __hip_atomic_store(&fidx[b * S_ + it], far + 1,
                                   __ATOMIC_RELAXED, __HIP_MEMORY_SCOPE_AGENT);
            float4 c = sc[far];
            vf2 c2x = (vf2){c.x, c.x}, c2y = (vf2){c.y, c.y}, c2z = (vf2){c.z, c.z};
#pragma unroll
            for (int q = 0; q < 8; ++q) {
                vf2 dx = pk_sub(px2[q], c2x);
                vf2 dy = pk_sub(py2[q], c2y);
                vf2 dz = pk_sub(pz2[q], c2z);
                vf2 d  = pk_fma(dz, dz, pk_fma(dy, dy, dx * dx));
                mind2[q] = pk_min(mind2[q], d);
            }
            // per-lane max over 16 via 3-ary tree (exact; fuses to v_max3_f32)
            #define M_(j) (mind2[(j) >> 1][(j) & 1])
            float g0 = max3f(M_(0),  M_(1),  M_(2));
            float g1 = max3f(M_(3),  M_(4),  M_(5));
            float g2 = max3f(M_(6),  M_(7),  M_(8));
            float g3 = max3f(M_(9),  M_(10), M_(11));
            float g4 = max3f(M_(12), M_(13), M_(14));
            float h0 = max3f(g0, g1, g2);
            float h1 = max3f(g3, g4, M_(15));
            float lmax = fmaxf(h0, h1);
            unsigned maxb = wavemax_bits_f(lmax);     // 6-stage DPP chain
            // LOCAL min-tree (depends only on lmb) issues in the DPP shadow.
            // Winner lane has lmb==maxb, so its local tree == global tree.
            unsigned lmb = __float_as_uint(lmax);
            int cj[16];
#pragma unroll
            for (int j = 0; j < 16; ++j)
                cj[j] = (__float_as_uint(M_(j)) == lmb) ? j : 64;
            #undef M_
            int n0m = min3i(cj[0],  cj[1],  cj[2]);
            int n1m = min3i(cj[3],  cj[4],  cj[5]);
            int n2m = min3i(cj[6],  cj[7],  cj[8]);
            int n3m = min3i(cj[9],  cj[10], cj[11]);
            int n4m = min3i(cj[12], cj[13], cj[14]);
            int p0m = min3i(n0m, n1m, n2m);
            int p1m = min3i(n3m, n4m, cj[15]);
            int minj_loc = min(p0m, p1m);
            unsigned long long mk = __ballot(lmb == maxb);
            int l0 = __ffsll((long long)mk) - 1;     // lowest lane = smallest n
            int jw = __builtin_amdgcn_readlane(minj_loc, l0);
            far = l0 * 16 + jw;
        }
        return;
    }

    // ================= conv123 worker (r15-verified, unchanged) =============
    const int CIp1 = 100, NK1 = 3;
    const int CIp2 = 72,  NK2 = 2;
    short* xsA    = (short*)smem;
    short* xsB    = xsA;                       // [256][72] overlay
    int*   gidx_l = (int*)(smem + 256 * 100 * 2);
    float* nxyz_l = (float*)(smem + 256 * 100 * 2 + 8 * K_ * 4);
    int*   fid_sh = (int*)(smem + 256 * 100 * 2 + 8 * K_ * 4 + 8 * 3 * 4);

    int w = blockIdx.x - 2;
    int lane = tid & 63;
    int wv   = tid >> 6;
    int l16  = lane & 15;
    int lq   = lane >> 4;

    for (int jobi = 0; jobi < 2; ++jobi) {
        int job = w + jobi * NWORK;
        int s = job >> 1, b = job & 1;
        __syncthreads();   // previous job's LDS reads retired

        // ---- tid0-only coarse->fine poll for fidx[b,s]; LDS broadcast ----
        if (tid == 0) {
            int guard = 0;
            int pre = s - 48;
            if (pre >= 0) {
                const int* pp = &fidx[b * S_ + pre];
                while (__hip_atomic_load(pp, __ATOMIC_RELAXED, __HIP_MEMORY_SCOPE_AGENT) == 0
                       && ++guard < (1 << 22))
                    __builtin_amdgcn_s_sleep(32);
            }
            const int* p = &fidx[b * S_ + s];
            int v = 0;
            do {
                v = __hip_atomic_load(p, __ATOMIC_RELAXED, __HIP_MEMORY_SCOPE_AGENT);
                if (v) break;
                __builtin_amdgcn_s_sleep(1);
            } while (++guard < (1 << 24));
            *fid_sh = v;
        }
        __syncthreads();
        int fid = *fid_sh - 1;

        // ---- phase 1: ball query (verified, break-free) ----
        for (int half = 0; half < 2; ++half) {
            int tt = wv * 2 + half;
            int bt = b * T_ + tt;
            const float* bx = xyz + (size_t)bt * 3 * NPTS;
            float nx = bx[fid], ny = bx[NPTS + fid], nz = bx[2 * NPTS + fid];
            if (lane < 3) {
                float vvv = (lane == 0) ? nx : ((lane == 1) ? ny : nz);
                out0[(bt * 3 + lane) * S_ + s] = vvv;   // [B,t,3,S]
                nxyz_l[tt * 3 + lane] = vvv;
            }
            float A = __fmaf_rn(nz, nz, __fmaf_rn(ny, ny, __fmul_rn(nx, nx)));
            const float R2 = (float)(0.2 * 0.2);
            int count = 0, firstIdx = -1;
#pragma unroll
            for (int j = 0; j < 16; ++j) {
                int n = j * 64 + lane;
                float x = bx[n], y = bx[NPTS + n], z = bx[2 * NPTS + n];
                float Bn = __fmaf_rn(z, z, __fmaf_rn(y, y, __fmul_rn(x, x)));
                float C  = __fmaf_rn(nz, z, __fmaf_rn(ny, y, __fmul_rn(nx, x)));
                float sq = __fsub_rn(__fadd_rn(A, Bn), __fmul_rn(2.0f, C));
                bool valid = !(sq > R2);
                unsigned long long mb = __ballot(valid);
                if (valid) {
                    int pos = count + __popcll(mb & ((1ull << lane) - 1ull));
                    if (pos < K_) gidx_l[tt * K_ + pos] = n;
                }
                if (firstIdx < 0 && mb) firstIdx = j * 64 + (__ffsll((long long)mb) - 1);
                count += __popcll(mb);
            }
            if (count < K_) {
                for (int p = count + lane; p < K_; p += 64) gidx_l[tt * K_ + p] = firstIdx;
            }
        }
        __syncthreads();

        // ---- phase 2: gather into xsA[col][0..100) ----
        {
            int col = tid;
            int k = col & 31, tt = col >> 5;
            int bt = b * T_ + tt;
            short* xrow = &xsA[col * CIp1];
            int idx = gidx_l[tt * K_ + k];
            const short* prow = ptsT + ((size_t)bt * NPTS + idx) * 64;
#pragma unroll
            for (int c = 0; c < 8; ++c)
                ((int4*)xrow)[c] = ((const int4*)prow)[c];
#pragma unroll
            for (int ci = 0; ci < 3; ++ci)
                xrow[64 + ci] = f2bf(xyz[(size_t)(bt * 3 + ci) * NPTS + idx] - nxyz_l[tt * 3 + ci]);
            for (int ci = 67; ci < CIp1; ++ci) xrow[ci] = 0;
        }
        __syncthreads();

        // ---- phase 3: L1 GEMM ----
        {
            f32x4 acc[16];
#pragma unroll
            for (int nb = 0; nb < 16; ++nb) acc[nb] = (f32x4){0.f, 0.f, 0.f, 0.f};
#pragma unroll
            for (int ks = 0; ks < NK1; ++ks) {
                bf16x8 afr[4];
#pragma unroll
                for (int dt = 0; dt < 4; ++dt)
                    afr[dt] = *(const bf16x8*)&wg0[((size_t)(dt * 64 + wv * 16 + l16)) * CIp1 + ks * 32 + lq * 8];
                bf16x8 bfr[16];
#pragma unroll
                for (int cb = 0; cb < 16; ++cb)
                    bfr[cb] = *(const bf16x8*)&xsA[(cb * 16 + l16) * CIp1 + ks * 32 + lq * 8];
#pragma unroll
                for (int dt = 0; dt < 4; ++dt) {
#pragma unroll
                    for (int nb = 0; nb < 16; ++nb) {
                        int cb = nb + (dt - 1) * 2;
                        if (cb >= 0 && cb < 16)
                            acc[nb] = __builtin_amdgcn_mfma_f32_16x16x32_bf16(
                                afr[dt], bfr[cb], acc[nb], 0, 0, 0);
                    }
                }
            }
            __syncthreads();   // L1 LDS reads retired -> xsA reusable
            float sc0[4], c20[4];
#pragma unroll
            for (int j = 0; j < 4; ++j) {
                int co = wv * 16 + lq * 4 + j;
                float scv = gg0[co] / sqrtf(vv0[co] + 1e-5f);
                sc0[j] = scv;
                c20[j] = (bb0[co] - mm0[co]) * scv + be0[co];
            }
#pragma unroll
            for (int nb = 0; nb < 16; ++nb) {
                int col = nb * 16 + l16;
                short4v pk;
#pragma unroll
                for (int j = 0; j < 4; ++j)
                    pk[j] = f2bf(fmaxf(acc[nb][j] * sc0[j] + c20[j], 0.0f));
                *(short4v*)&xsB[col * CIp2 + wv * 16 + lq * 4] = pk;
            }
            *(int4*)&xsB[tid * CIp2 + 64] = make_int4(0, 0, 0, 0);
        }
        __syncthreads();

        // ---- phase 4: L2 GEMM ----
        {
            f32x4 acc[16];
#pragma unroll
            for (int nb = 0; nb < 16; ++nb) acc[nb] = (f32x4){0.f, 0.f, 0.f, 0.f};
#pragma unroll
            for (int ks = 0; ks < NK2; ++ks) {
                bf16x8 afr[4];
#pragma unroll
                for (int dt = 0; dt < 4; ++dt)
                    afr[dt] = *(const bf16x8*)&wg1[((size_t)(dt * 64 + wv * 16 + l16)) * CIp2 + ks * 32 + lq * 8];
                bf16x8 bfr[16];
#pragma unroll
                for (int cb = 0; cb < 16; ++cb)
                    bfr[cb] = *(const bf16x8*)&xsB[(cb * 16 + l16) * CIp2 + ks * 32 + lq * 8];
#pragma unroll
                for (int dt = 0; dt < 4; ++dt) {
#pragma unroll
                    for (int nb = 0; nb < 16; ++nb) {
                        int cb = nb + (dt - 1) * 2;
                        if (cb >= 0 && cb < 16)
                            acc[nb] = __builtin_amdgcn_mfma_f32_16x16x32_bf16(
                                afr[dt], bfr[cb], acc[nb], 0, 0, 0);
                    }
                }
            }
            __syncthreads();   // L2 LDS reads retired -> xsB writable
            float sc1[4], c21[4];
#pragma unroll
            for (int j = 0; j < 4; ++j) {
                int co = wv * 16 + lq * 4 + j;
                float scv = gg1[co] / sqrtf(vv1[co] + 1e-5f);
                sc1[j] = scv;
                c21[j] = (bb1[co] - mm1[co]) * scv + be1[co];
            }
#pragma unroll
            for (int nb = 0; nb < 16; ++nb) {
                int col = nb * 16 + l16;
                short4v pk;
#pragma unroll
                for (int j = 0; j < 4; ++j)
                    pk[j] = f2bf(fmaxf(acc[nb][j] * sc1[j] + c21[j], 0.0f));
                *(short4v*)&xsB[col * CIp2 + wv * 16 + lq * 4] = pk;
            }
        }
        __syncthreads();

        // ---- phase 5: L3 GEMM + pool ----
#pragma unroll
        for (int st = 0; st < 2; ++st) {
            f32x4 acc[16];
#pragma unroll
            for (int nb = 0; nb < 16; ++nb) acc[nb] = (f32x4){0.f, 0.f, 0.f, 0.f};
#pragma unroll
            for (int ks = 0; ks < NK2; ++ks) {
                bf16x8 afr[4];
#pragma unroll
                for (int dt = 0; dt < 4; ++dt)
                    afr[dt] = *(const bf16x8*)&wg2[((size_t)(dt * 128 + st * 64 + wv * 16 + l16)) * CIp2 + ks * 32 + lq * 8];
                bf16x8 bfr[16];
#pragma unroll
                for (int cb = 0; cb < 16; ++cb)
                    bfr[cb] = *(const bf16x8*)&xsB[(cb * 16 + l16) * CIp2 + ks * 32 + lq * 8];
#pragma unroll
                for (int dt = 0; dt < 4; ++dt) {
#pragma unroll
                    for (int nb = 0; nb < 16; ++nb) {
                        int cb = nb + (dt - 1) * 2;
                        if (cb >= 0 && cb < 16)
                            acc[nb] = __builtin_amdgcn_mfma_f32_16x16x32_bf16(
                                afr[dt], bfr[cb], acc[nb], 0, 0, 0);
                    }
                }
            }
            float sc2[4], c22[4];
#pragma unroll
            for (int j = 0; j < 4; ++j) {
                int co = st * 64 + wv * 16 + lq * 4 + j;
                float scv = gg2[co] / sqrtf(vv2[co] + 1e-5f);
                sc2[j] = scv;
                c22[j] = (bb2[co] - mm2[co]) * scv + be2[co];
            }
#pragma unroll
            for (int nbp = 0; nbp < 8; ++nbp) {       // t = nbp
#pragma unroll
                for (int j = 0; j < 4; ++j) {
                    float v0 = fmaxf(acc[2 * nbp][j] * sc2[j] + c22[j], 0.0f);
                    float v1 = fmaxf(acc[2 * nbp + 1][j] * sc2[j] + c22[j], 0.0f);
                    float v = fmaxf(v0, v1);
#pragma unroll
                    for (int off = 1; off < 16; off <<= 1)
                        v = fmaxf(v, __shfl_xor(v, off));
                    if (l16 == 0) {
                        int co = st * 64 + wv * 16 + lq * 4 + j;
                        outPool[((size_t)(b * T_ + nbp) * 128 + co) * S_ + s] = v;
                    }
                }
            }
        }
    }
}

// ---------------------------------------------------------------------------
extern "C" void kernel_launch(void* const* d_in, const int* in_sizes, int n_in,
                              void* d_out, int out_size, void* d_ws, size_t ws_size,
                              hipStream_t stream)
{
    (void)in_sizes; (void)n_in; (void)out_size; (void)ws_size;
    const float* xyz    = (const float*)d_in[0];
    const float* points = (const float*)d_in[1];
    const float* w0 = (const float*)d_in[2];
    const float* b0 = (const float*)d_in[3];
    const float* g0 = (const float*)d_in[4];
    const float* be0 = (const float*)d_in[5];
    const float* m0 = (const float*)d_in[6];
    const float* v0 = (const float*)d_in[7];
    const float* w1 = (const float*)d_in[8];
    const float* b1 = (const float*)d_in[9];
    const float* g1 = (const float*)d_in[10];
    const float* be1 = (const float*)d_in[11];
    const float* m1 = (const float*)d_in[12];
    const float* v1 = (const float*)d_in[13];
    const float* w2 = (const float*)d_in[14];
    const float* b2 = (const float*)d_in[15];
    const float* g2 = (const float*)d_in[16];
    const float* be2 = (const float*)d_in[17];
    const float* m2 = (const float*)d_in[18];
    const float* v2 = (const float*)d_in[19];

    float* out = (float*)d_out;
    char* ws = (char*)d_ws;
    // workspace map:
    //   fidx  @ 0        :   4 KB  (zeroed each launch; value = far+1)
    //   wg0   @ 3 MB     :  51.2 KB
    //   wg1   @ 3.25 MB  :  36.9 KB
    //   wg2   @ 3.5 MB   :  73.7 KB
    //   ptsT  @ 4  MB    :  2.1 MB
    int*   fidx = (int*)ws;
    short* wg0  = (short*)(ws + (size_t)(3 * 1024 * 1024));
    short* wg1  = (short*)(ws + (size_t)(3 * 1024 * 1024) + 256 * 1024);
    short* wg2  = (short*)(ws + (size_t)(3 * 1024 * 1024) + 512 * 1024);
    short* ptsT = (short*)(ws + (size_t)(4  * 1024 * 1024));

    hipMemsetAsync(fidx, 0, B_ * S_ * sizeof(int), stream);
    prep_all<<<dim3(144, 3), 256, 0, stream>>>(w0, w1, w2, wg0, wg1, wg2);
    transpose_points<<<dim3(16, B_ * T_), 256, 0, stream>>>(points, ptsT);

    mega<<<dim3(2 + NWORK), 256, 0, stream>>>(
        xyz, ptsT, fidx,
        wg0, b0, g0, be0, m0, v0,
        wg1, b1, g1, be1, m1, v1,
        wg2, b2, g2, be2, m2, v2,
        out, out + (size_t)B_ * T_ * 3 * S_);
}